// Round 6
// baseline (568.343 us; speedup 1.0000x reference)
//
#include <hip/hip_runtime.h>
#include <hip/hip_bf16.h>
#include <stdint.h>

// Problem constants: B=8, N=1024, C=1024, H=16, D=64, M=B*N=8192
#define M_ROWS 8192
#define C_DIM  1024
#define QKV_N  3072

typedef _Float16 f16;
typedef __attribute__((ext_vector_type(8))) _Float16 f16x8;   // 4 VGPRs
typedef __attribute__((ext_vector_type(8))) short short8_t;   // 8 bf16
typedef __attribute__((ext_vector_type(4))) float float4_t;   // 4 fp32 acc
typedef unsigned short u16;
typedef unsigned int u32;

__device__ __forceinline__ u16 f16_bits(float x) {
  union { f16 h; u16 u; } c; c.h = (f16)x; return c.u;
}
__device__ __forceinline__ u16 f32_to_bf16(float f) {
  u32 u = __float_as_uint(f);
  u32 r = (u + 0x7fffu + ((u >> 16) & 1u)) >> 16;  // RNE
  return (u16)r;
}
__device__ __forceinline__ float bf16_to_f32(u16 h) {
  return __uint_as_float((u32)h << 16);
}
__device__ __forceinline__ void gld_lds16(const void* g, void* l) {
  __builtin_amdgcn_global_load_lds(
      (const __attribute__((address_space(1))) u32*)g,
      (__attribute__((address_space(3))) u32*)l, 16, 0, 0);
}

// ---------------------------------------------------------------------------
// split fp32 -> (hi, lo) bf16 pair; 4 elems/thread
// ---------------------------------------------------------------------------
__global__ __launch_bounds__(256) void split_bf16(
    const float* __restrict__ in, u16* __restrict__ hi, u16* __restrict__ lo) {
  int i = blockIdx.x * 256 + threadIdx.x;
  float4 v = ((const float4*)in)[i];
  float x[4] = {v.x, v.y, v.z, v.w};
  union { u16 u[4]; uint2 v2; } H, L;
#pragma unroll
  for (int j = 0; j < 4; ++j) {
    u16 h = f32_to_bf16(x[j]);
    H.u[j] = h;
    L.u[j] = f32_to_bf16(x[j] - bf16_to_f32(h));
  }
  ((uint2*)hi)[i] = H.v2;
  ((uint2*)lo)[i] = L.v2;
}

// ---------------------------------------------------------------------------
// Split-bf16 MFMA GEMM (Ah+Al)@(Bh+Bl)^T + bias, drops Al*Bl (fp32-grade).
// 128x128 tile, BK=32, 256 thr (4 waves 2x2), 16x16x32_bf16, m97 structure.
// MODE 0: QKV — fused per-head RMSNorm on sections 0,1; writes fp16 q,k,v.
// MODE 1: proj — fp32 + bias to O0 (the final output).
// ---------------------------------------------------------------------------
template <int MODE>
__global__ __launch_bounds__(256) void gemm_split(
    const u16* __restrict__ Ah, const u16* __restrict__ Al,
    const u16* __restrict__ Bh, const u16* __restrict__ Bl,
    const float* __restrict__ bias, void* __restrict__ O0,
    void* __restrict__ O1, void* __restrict__ O2,
    const float* __restrict__ qn_w, const float* __restrict__ kn_w,
    int M, int N, int K) {
  __shared__ u16 sAh[128 * 32], sAl[128 * 32], sBh[128 * 32], sBl[128 * 32];
  const int t = threadIdx.x;
  const int wv = t >> 6;
  const int lane = t & 63;
  const int n0 = blockIdx.x * 128;
  const int m0 = blockIdx.y * 128;
  const int wm = wv >> 1, wn = wv & 1;
  const int fr = lane & 15;
  const int g = lane >> 4;
  const int kfr = g * 8;

  float4_t acc[4][4];
  const float4_t zero = {0.f, 0.f, 0.f, 0.f};
#pragma unroll
  for (int i = 0; i < 4; ++i)
#pragma unroll
    for (int j = 0; j < 4; ++j) acc[i][j] = zero;

  for (int k0 = 0; k0 < K; k0 += 32) {
#pragma unroll
    for (int u = 0; u < 2; ++u) {
      int idx = u * 256 + t;
      int row = idx >> 2;
      int ke = (idx & 3) * 8;
      int ldsoff = (u * 256 + wv * 64) * 8;  // wave-uniform base (elems)
      const size_t ga = (size_t)(m0 + row) * K + k0 + ke;
      const size_t gb = (size_t)(n0 + row) * K + k0 + ke;
      gld_lds16(Ah + ga, sAh + ldsoff);
      gld_lds16(Al + ga, sAl + ldsoff);
      gld_lds16(Bh + gb, sBh + ldsoff);
      gld_lds16(Bl + gb, sBl + ldsoff);
    }
    __syncthreads();

    short8_t ah[4], al[4], bh[4], bl[4];
#pragma unroll
    for (int i = 0; i < 4; ++i) {
      ah[i] = *(const short8_t*)&sAh[(wm * 64 + i * 16 + fr) * 32 + kfr];
      al[i] = *(const short8_t*)&sAl[(wm * 64 + i * 16 + fr) * 32 + kfr];
      bh[i] = *(const short8_t*)&sBh[(wn * 64 + i * 16 + fr) * 32 + kfr];
      bl[i] = *(const short8_t*)&sBl[(wn * 64 + i * 16 + fr) * 32 + kfr];
    }
#pragma unroll
    for (int i = 0; i < 4; ++i)
#pragma unroll
      for (int j = 0; j < 4; ++j) {
        acc[i][j] = __builtin_amdgcn_mfma_f32_16x16x32_bf16(ah[i], bh[j], acc[i][j], 0, 0, 0);
        acc[i][j] = __builtin_amdgcn_mfma_f32_16x16x32_bf16(ah[i], bl[j], acc[i][j], 0, 0, 0);
        acc[i][j] = __builtin_amdgcn_mfma_f32_16x16x32_bf16(al[i], bh[j], acc[i][j], 0, 0, 0);
      }
    __syncthreads();
  }

  // Epilogue. C/D layout: col=lane&15, row=(lane>>4)*4+reg.
  const int r0 = g * 4;
  const int nw = n0 + wn * 64;  // wave col base; 64-aligned -> exactly 1 head
  float bz[4];
#pragma unroll
  for (int j = 0; j < 4; ++j) bz[j] = bias[nw + j * 16 + fr];

  if (MODE == 0) {
    const int sec = nw >> 10;           // 0=q 1=k 2=v
    const int h = (nw >> 6) & 15;
    u16* O = (sec == 0) ? (u16*)O0 : ((sec == 1) ? (u16*)O1 : (u16*)O2);
    float wn_[4];
    if (sec < 2) {
      const float* wvec = (sec == 0) ? qn_w : kn_w;
#pragma unroll
      for (int j = 0; j < 4; ++j) wn_[j] = wvec[j * 16 + fr];
    }
#pragma unroll
    for (int i = 0; i < 4; ++i) {
      float val[4][4];  // [j][r]
#pragma unroll
      for (int j = 0; j < 4; ++j)
#pragma unroll
        for (int r = 0; r < 4; ++r) val[j][r] = acc[i][j][r] + bz[j];
      if (sec < 2) {
        // RMS over the head's 64 cols: 4 j-regs x 16 fr-lanes (same g, same r)
#pragma unroll
        for (int r = 0; r < 4; ++r) {
          float ss = 0.f;
#pragma unroll
          for (int j = 0; j < 4; ++j) ss += val[j][r] * val[j][r];
#pragma unroll
          for (int mask = 8; mask >= 1; mask >>= 1) ss += __shfl_xor(ss, mask);
          float sc = rsqrtf(ss * (1.0f / 64.0f) + 1e-6f);
#pragma unroll
          for (int j = 0; j < 4; ++j) val[j][r] *= sc * wn_[j];
        }
      }
#pragma unroll
      for (int j = 0; j < 4; ++j) {
        int col = h * 64 + j * 16 + fr;
#pragma unroll
        for (int r = 0; r < 4; ++r) {
          int m = m0 + wm * 64 + i * 16 + r0 + r;
          O[(size_t)m * 1024 + col] = f16_bits(val[j][r]);
        }
      }
    }
  } else {
    float* O = (float*)O0;
#pragma unroll
    for (int j = 0; j < 4; ++j) {
      int n = nw + j * 16 + fr;
#pragma unroll
      for (int i = 0; i < 4; ++i) {
        int mb = m0 + wm * 64 + i * 16 + r0;
#pragma unroll
        for (int r = 0; r < 4; ++r)
          O[(size_t)(mb + r) * 1024 + n] = acc[i][j][r] + bz[j];
      }
    }
  }
}

// ---------------------------------------------------------------------------
// V transpose: v fp16 [8192][1024] -> vt fp16 [bh=128][d=64][n=1024]
// ---------------------------------------------------------------------------
__global__ __launch_bounds__(256) void vtrans16(const u16* __restrict__ v,
                                                u16* __restrict__ vt) {
  __shared__ __align__(16) u16 T[64][80];
  const int t = threadIdx.x;
  const int nb = blockIdx.x;   // 16 n-tiles
  const int bh = blockIdx.y;   // 128
  const int b = bh >> 4, h = bh & 15;
  const int n0 = nb * 64;
#pragma unroll
  for (int u = 0; u < 2; ++u) {
    int idx = u * 256 + t;       // 0..511
    int row = idx >> 3;          // n 0..63
    int c8 = (idx & 7) * 8;      // d chunk
    uint4 val = *(const uint4*)&v[((size_t)(b * 1024 + n0 + row)) * 1024 + h * 64 + c8];
    *(uint4*)&T[row][c8] = val;
  }
  __syncthreads();
#pragma unroll
  for (int u = 0; u < 2; ++u) {
    int idx = u * 256 + t;
    int d = idx >> 3;            // 0..63
    int n8 = (idx & 7) * 8;
    union { u16 q[8]; uint4 v4; } P;
#pragma unroll
    for (int i = 0; i < 8; ++i) P.q[i] = T[n8 + i][d];
    *(uint4*)&vt[((size_t)bh * 64 + d) * 1024 + n0 + n8] = P.v4;
  }
}

// ---------------------------------------------------------------------------
// Staging-free MFMA flash attention (fp16 in, bf16 hi/lo out). 4 indep
// waves/block, 16 q-rows each; K/V/Q fragments straight from global
// (L1/L2-resident); only P round-trips through wave-local LDS. Zero barriers.
// ---------------------------------------------------------------------------
__global__ __launch_bounds__(256) void flash_f16(
    const u16* __restrict__ q, const u16* __restrict__ k,
    const u16* __restrict__ vt, u16* __restrict__ ao_hi,
    u16* __restrict__ ao_lo) {
  __shared__ __align__(16) u16 sP[4][16][88];  // [wave][row][col pad]
  const int t = threadIdx.x;
  const int wv = t >> 6, lane = t & 63;
  const int fr = lane & 15;   // A-frag row / D col
  const int g = lane >> 4;    // k-chunk group; D rows g*4+r
  // Bijective XCD-chunk swizzle: 2048 blocks = 8 xcd x 256.
  int flat = blockIdx.x;
  int nf = (flat & 7) * 256 + (flat >> 3);
  const int qb = nf & 15, bh = nf >> 4;
  const int q0 = qb * 64;
  const int b = bh >> 4, h = bh & 15;

  const u16* qrow = q + ((size_t)(b * 1024 + q0 + wv * 16 + fr)) * 1024 + h * 64;
  const u16* krow = k + ((size_t)b * 1024) * 1024 + h * 64;
  const u16* vbase = vt + (size_t)bh * 64 * 1024;

  f16x8 aQ[2];
#pragma unroll
  for (int c = 0; c < 2; ++c)
    aQ[c] = *(const f16x8*)&qrow[c * 32 + g * 8];

  float m_run[4], l_run[4];
  float4_t o[4];
  const float4_t zero = {0.f, 0.f, 0.f, 0.f};
#pragma unroll
  for (int r = 0; r < 4; ++r) { m_run[r] = -1e30f; l_run[r] = 0.f; }
#pragma unroll
  for (int dt = 0; dt < 4; ++dt) o[dt] = zero;
  const float scale = 0.125f;

  for (int k0 = 0; k0 < 1024; k0 += 64) {
    // QK^T: 8 MFMA, B-frags straight from global K rows
    float4_t sac[4];
#pragma unroll
    for (int j = 0; j < 4; ++j) sac[j] = zero;
#pragma unroll
    for (int j = 0; j < 4; ++j) {
      f16x8 kb0 = *(const f16x8*)&krow[(size_t)(k0 + j * 16 + fr) * 1024 + g * 8];
      f16x8 kb1 = *(const f16x8*)&krow[(size_t)(k0 + j * 16 + fr) * 1024 + 32 + g * 8];
      __builtin_amdgcn_s_setprio(1);
      sac[j] = __builtin_amdgcn_mfma_f32_16x16x32_f16(aQ[0], kb0, sac[j], 0, 0, 0);
      sac[j] = __builtin_amdgcn_mfma_f32_16x16x32_f16(aQ[1], kb1, sac[j], 0, 0, 0);
      __builtin_amdgcn_s_setprio(0);
    }

    // Online softmax; lane's S rows are g*4+r, col j*16+fr
    float corr[4];
#pragma unroll
    for (int r = 0; r < 4; ++r) {
      float p0 = sac[0][r] * scale, p1 = sac[1][r] * scale;
      float p2 = sac[2][r] * scale, p3 = sac[3][r] * scale;
      float mx = fmaxf(fmaxf(p0, p1), fmaxf(p2, p3));
#pragma unroll
      for (int mask = 8; mask >= 1; mask >>= 1)
        mx = fmaxf(mx, __shfl_xor(mx, mask));
      float m_new = fmaxf(m_run[r], mx);
      corr[r] = __expf(m_run[r] - m_new);
      p0 = __expf(p0 - m_new); p1 = __expf(p1 - m_new);
      p2 = __expf(p2 - m_new); p3 = __expf(p3 - m_new);
      float rs = p0 + p1 + p2 + p3;
#pragma unroll
      for (int mask = 8; mask >= 1; mask >>= 1) rs += __shfl_xor(rs, mask);
      l_run[r] = fmaf(l_run[r], corr[r], rs);
      m_run[r] = m_new;
      int row = g * 4 + r;
      sP[wv][row][0 * 16 + fr] = f16_bits(p0);
      sP[wv][row][1 * 16 + fr] = f16_bits(p1);
      sP[wv][row][2 * 16 + fr] = f16_bits(p2);
      sP[wv][row][3 * 16 + fr] = f16_bits(p3);
    }

    // Rescale O (skip when every corr==1 -> exact identity)
    bool noscale = (corr[0] == 1.f) & (corr[1] == 1.f) &
                   (corr[2] == 1.f) & (corr[3] == 1.f);
    if (!__all(noscale)) {
#pragma unroll
      for (int dt = 0; dt < 4; ++dt)
#pragma unroll
        for (int r = 0; r < 4; ++r) o[dt][r] *= corr[r];
    }

    // PV: A-frags from wave-local sP (intra-wave dep, no barrier), B from vt
    f16x8 pa[2];
#pragma unroll
    for (int c = 0; c < 2; ++c)
      pa[c] = *(const f16x8*)&sP[wv][fr][c * 32 + g * 8];
#pragma unroll
    for (int dt = 0; dt < 4; ++dt) {
      f16x8 vb0 = *(const f16x8*)&vbase[(size_t)(dt * 16 + fr) * 1024 + k0 + g * 8];
      f16x8 vb1 = *(const f16x8*)&vbase[(size_t)(dt * 16 + fr) * 1024 + k0 + 32 + g * 8];
      __builtin_amdgcn_s_setprio(1);
      o[dt] = __builtin_amdgcn_mfma_f32_16x16x32_f16(pa[0], vb0, o[dt], 0, 0, 0);
      o[dt] = __builtin_amdgcn_mfma_f32_16x16x32_f16(pa[1], vb1, o[dt], 0, 0, 0);
      __builtin_amdgcn_s_setprio(0);
    }
  }

  // Epilogue: normalize, split bf16 hi/lo for the split proj GEMM
#pragma unroll
  for (int r = 0; r < 4; ++r) {
    float inv = 1.0f / l_run[r];
    int qg = q0 + wv * 16 + g * 4 + r;
#pragma unroll
    for (int dt = 0; dt < 4; ++dt) {
      float v = o[dt][r] * inv;
      u16 hb = f32_to_bf16(v);
      size_t off = ((size_t)(b * 1024 + qg)) * 1024 + h * 64 + dt * 16 + fr;
      ao_hi[off] = hb;
      ao_lo[off] = f32_to_bf16(v - bf16_to_f32(hb));
    }
  }
}

// ---------------------------------------------------------------------------
extern "C" void kernel_launch(void* const* d_in, const int* in_sizes, int n_in,
                              void* d_out, int out_size, void* d_ws, size_t ws_size,
                              hipStream_t stream) {
  const float* x      = (const float*)d_in[0];
  const float* w_qkv  = (const float*)d_in[1];
  const float* b_qkv  = (const float*)d_in[2];
  const float* qn_w   = (const float*)d_in[3];
  const float* kn_w   = (const float*)d_in[4];
  const float* w_proj = (const float*)d_in[5];
  const float* b_proj = (const float*)d_in[6];
  float* out = (float*)d_out;

  // ws layout, all u16 (~144 MB)
  u16* x_hi  = (u16*)d_ws;          // 8192*1024
  u16* x_lo  = x_hi + 8388608;
  u16* wq_hi = x_lo + 8388608;      // 3072*1024
  u16* wq_lo = wq_hi + 3145728;
  u16* wp_hi = wq_lo + 3145728;     // 1024*1024
  u16* wp_lo = wp_hi + 1048576;
  u16* qb    = wp_lo + 1048576;     // fp16 q [8192][1024]
  u16* kb    = qb + 8388608;        // fp16 k
  u16* vb    = kb + 8388608;        // fp16 v
  u16* vtb   = vb + 8388608;        // fp16 v^T [128][64][1024]
  u16* ao_hi = vtb + 8388608;       // bf16 attn-out hi
  u16* ao_lo = ao_hi + 8388608;     // bf16 attn-out lo

  split_bf16<<<8192, 256, 0, stream>>>(x, x_hi, x_lo);
  split_bf16<<<3072, 256, 0, stream>>>(w_qkv, wq_hi, wq_lo);
  split_bf16<<<1024, 256, 0, stream>>>(w_proj, wp_hi, wp_lo);

  // QKV projection (split-bf16, fp32-grade) + fused RMSNorm -> fp16 q,k,v
  gemm_split<0><<<dim3(QKV_N / 128, M_ROWS / 128), 256, 0, stream>>>(
      x_hi, x_lo, wq_hi, wq_lo, b_qkv, qb, kb, vb, qn_w, kn_w,
      M_ROWS, QKV_N, C_DIM);

  vtrans16<<<dim3(16, 128), 256, 0, stream>>>(vb, vtb);

  flash_f16<<<2048, 256, 0, stream>>>(qb, kb, vtb, ao_hi, ao_lo);

  // Output projection (split-bf16) -> fp32 out
  gemm_split<1><<<dim3(C_DIM / 128, M_ROWS / 128), 256, 0, stream>>>(
      ao_hi, ao_lo, wp_hi, wp_lo, b_proj, out, nullptr, nullptr,
      nullptr, nullptr, M_ROWS, C_DIM, C_DIM);
}

// Round 7
// 448.547 us; speedup vs baseline: 1.2671x; 1.2671x over previous
//
#include <hip/hip_runtime.h>
#include <hip/hip_bf16.h>
#include <stdint.h>

// Problem constants: B=8, N=1024, C=1024, H=16, D=64, M=B*N=8192
#define M_ROWS 8192
#define C_DIM  1024
#define QKV_N  3072

typedef _Float16 f16;
typedef __attribute__((ext_vector_type(8))) _Float16 f16x8;   // 4 VGPRs
typedef __attribute__((ext_vector_type(8))) short short8_t;   // 8 bf16
typedef __attribute__((ext_vector_type(4))) float float4_t;   // 4 fp32 acc
typedef unsigned short u16;
typedef unsigned int u32;

__device__ __forceinline__ u16 f16_bits(float x) {
  union { f16 h; u16 u; } c; c.h = (f16)x; return c.u;
}
__device__ __forceinline__ u16 f32_to_bf16(float f) {
  u32 u = __float_as_uint(f);
  u32 r = (u + 0x7fffu + ((u >> 16) & 1u)) >> 16;  // RNE
  return (u16)r;
}
__device__ __forceinline__ float bf16_to_f32(u16 h) {
  return __uint_as_float((u32)h << 16);
}
__device__ __forceinline__ void gld_lds16(const void* g, void* l) {
  __builtin_amdgcn_global_load_lds(
      (const __attribute__((address_space(1))) u32*)g,
      (__attribute__((address_space(3))) u32*)l, 16, 0, 0);
}
// Swizzled elem offset in a [64][64]-fp16 LDS tile (row len 128B):
// byte ^= ((row&7)<<4)  <=>  elem ^= ((row&7)<<3)
__device__ __forceinline__ int elem_off(int row, int e0) {
  return row * 64 + (e0 ^ ((row & 7) << 3));
}

// ---------------------------------------------------------------------------
// split fp32 -> (hi, lo) bf16 pair; 4 elems/thread
// ---------------------------------------------------------------------------
__global__ __launch_bounds__(256) void split_bf16(
    const float* __restrict__ in, u16* __restrict__ hi, u16* __restrict__ lo) {
  int i = blockIdx.x * 256 + threadIdx.x;
  float4 v = ((const float4*)in)[i];
  float x[4] = {v.x, v.y, v.z, v.w};
  union { u16 u[4]; uint2 v2; } H, L;
#pragma unroll
  for (int j = 0; j < 4; ++j) {
    u16 h = f32_to_bf16(x[j]);
    H.u[j] = h;
    L.u[j] = f32_to_bf16(x[j] - bf16_to_f32(h));
  }
  ((uint2*)hi)[i] = H.v2;
  ((uint2*)lo)[i] = L.v2;
}

// ---------------------------------------------------------------------------
// Split-bf16 MFMA GEMM (Ah+Al)@(Bh+Bl)^T + bias, drops Al*Bl (fp32-grade).
// 128x128 tile, BK=32, 256 thr (4 waves 2x2), 16x16x32_bf16, m97 structure.
// MODE 0: QKV — fused per-head RMSNorm on sections 0,1; writes fp16 q,k,v.
// MODE 1: proj — fp32 + bias to O0 (the final output).
// ---------------------------------------------------------------------------
template <int MODE>
__global__ __launch_bounds__(256) void gemm_split(
    const u16* __restrict__ Ah, const u16* __restrict__ Al,
    const u16* __restrict__ Bh, const u16* __restrict__ Bl,
    const float* __restrict__ bias, void* __restrict__ O0,
    void* __restrict__ O1, void* __restrict__ O2,
    const float* __restrict__ qn_w, const float* __restrict__ kn_w,
    int M, int N, int K) {
  __shared__ u16 sAh[128 * 32], sAl[128 * 32], sBh[128 * 32], sBl[128 * 32];
  const int t = threadIdx.x;
  const int wv = t >> 6;
  const int lane = t & 63;
  const int n0 = blockIdx.x * 128;
  const int m0 = blockIdx.y * 128;
  const int wm = wv >> 1, wn = wv & 1;
  const int fr = lane & 15;
  const int g = lane >> 4;
  const int kfr = g * 8;

  float4_t acc[4][4];
  const float4_t zero = {0.f, 0.f, 0.f, 0.f};
#pragma unroll
  for (int i = 0; i < 4; ++i)
#pragma unroll
    for (int j = 0; j < 4; ++j) acc[i][j] = zero;

  for (int k0 = 0; k0 < K; k0 += 32) {
#pragma unroll
    for (int u = 0; u < 2; ++u) {
      int idx = u * 256 + t;
      int row = idx >> 2;
      int ke = (idx & 3) * 8;
      int ldsoff = (u * 256 + wv * 64) * 8;  // wave-uniform base (elems)
      const size_t ga = (size_t)(m0 + row) * K + k0 + ke;
      const size_t gb = (size_t)(n0 + row) * K + k0 + ke;
      gld_lds16(Ah + ga, sAh + ldsoff);
      gld_lds16(Al + ga, sAl + ldsoff);
      gld_lds16(Bh + gb, sBh + ldsoff);
      gld_lds16(Bl + gb, sBl + ldsoff);
    }
    __syncthreads();

    short8_t ah[4], al[4], bh[4], bl[4];
#pragma unroll
    for (int i = 0; i < 4; ++i) {
      ah[i] = *(const short8_t*)&sAh[(wm * 64 + i * 16 + fr) * 32 + kfr];
      al[i] = *(const short8_t*)&sAl[(wm * 64 + i * 16 + fr) * 32 + kfr];
      bh[i] = *(const short8_t*)&sBh[(wn * 64 + i * 16 + fr) * 32 + kfr];
      bl[i] = *(const short8_t*)&sBl[(wn * 64 + i * 16 + fr) * 32 + kfr];
    }
#pragma unroll
    for (int i = 0; i < 4; ++i)
#pragma unroll
      for (int j = 0; j < 4; ++j) {
        acc[i][j] = __builtin_amdgcn_mfma_f32_16x16x32_bf16(ah[i], bh[j], acc[i][j], 0, 0, 0);
        acc[i][j] = __builtin_amdgcn_mfma_f32_16x16x32_bf16(ah[i], bl[j], acc[i][j], 0, 0, 0);
        acc[i][j] = __builtin_amdgcn_mfma_f32_16x16x32_bf16(al[i], bh[j], acc[i][j], 0, 0, 0);
      }
    __syncthreads();
  }

  // Epilogue. C/D layout: col=lane&15, row=(lane>>4)*4+reg.
  const int r0 = g * 4;
  const int nw = n0 + wn * 64;  // wave col base; 64-aligned -> exactly 1 head
  float bz[4];
#pragma unroll
  for (int j = 0; j < 4; ++j) bz[j] = bias[nw + j * 16 + fr];

  if (MODE == 0) {
    const int sec = nw >> 10;           // 0=q 1=k 2=v
    const int h = (nw >> 6) & 15;
    u16* O = (sec == 0) ? (u16*)O0 : ((sec == 1) ? (u16*)O1 : (u16*)O2);
    float wn_[4];
    if (sec < 2) {
      const float* wvec = (sec == 0) ? qn_w : kn_w;
#pragma unroll
      for (int j = 0; j < 4; ++j) wn_[j] = wvec[j * 16 + fr];
    }
#pragma unroll
    for (int i = 0; i < 4; ++i) {
      float val[4][4];  // [j][r]
#pragma unroll
      for (int j = 0; j < 4; ++j)
#pragma unroll
        for (int r = 0; r < 4; ++r) val[j][r] = acc[i][j][r] + bz[j];
      if (sec < 2) {
        // RMS over the head's 64 cols: 4 j-regs x 16 fr-lanes (same g, same r)
#pragma unroll
        for (int r = 0; r < 4; ++r) {
          float ss = 0.f;
#pragma unroll
          for (int j = 0; j < 4; ++j) ss += val[j][r] * val[j][r];
#pragma unroll
          for (int mask = 8; mask >= 1; mask >>= 1) ss += __shfl_xor(ss, mask);
          float sc = rsqrtf(ss * (1.0f / 64.0f) + 1e-6f);
#pragma unroll
          for (int j = 0; j < 4; ++j) val[j][r] *= sc * wn_[j];
        }
      }
#pragma unroll
      for (int j = 0; j < 4; ++j) {
        int col = h * 64 + j * 16 + fr;
#pragma unroll
        for (int r = 0; r < 4; ++r) {
          int m = m0 + wm * 64 + i * 16 + r0 + r;
          O[(size_t)m * 1024 + col] = f16_bits(val[j][r]);
        }
      }
    }
  } else {
    float* O = (float*)O0;
#pragma unroll
    for (int j = 0; j < 4; ++j) {
      int n = nw + j * 16 + fr;
#pragma unroll
      for (int i = 0; i < 4; ++i) {
        int mb = m0 + wm * 64 + i * 16 + r0;
#pragma unroll
        for (int r = 0; r < 4; ++r)
          O[(size_t)(mb + r) * 1024 + n] = acc[i][j][r] + bz[j];
      }
    }
  }
}

// ---------------------------------------------------------------------------
// V transpose: v fp16 [8192][1024] -> vt fp16 [bh=128][d=64][n=1024]
// ---------------------------------------------------------------------------
__global__ __launch_bounds__(256) void vtrans16(const u16* __restrict__ v,
                                                u16* __restrict__ vt) {
  __shared__ __align__(16) u16 T[64][80];
  const int t = threadIdx.x;
  const int nb = blockIdx.x;   // 16 n-tiles
  const int bh = blockIdx.y;   // 128
  const int b = bh >> 4, h = bh & 15;
  const int n0 = nb * 64;
#pragma unroll
  for (int u = 0; u < 2; ++u) {
    int idx = u * 256 + t;       // 0..511
    int row = idx >> 3;          // n 0..63
    int c8 = (idx & 7) * 8;      // d chunk
    uint4 val = *(const uint4*)&v[((size_t)(b * 1024 + n0 + row)) * 1024 + h * 64 + c8];
    *(uint4*)&T[row][c8] = val;
  }
  __syncthreads();
#pragma unroll
  for (int u = 0; u < 2; ++u) {
    int idx = u * 256 + t;
    int d = idx >> 3;            // 0..63
    int n8 = (idx & 7) * 8;
    union { u16 q[8]; uint4 v4; } P;
#pragma unroll
    for (int i = 0; i < 8; ++i) P.q[i] = T[n8 + i][d];
    *(uint4*)&vt[((size_t)bh * 64 + d) * 1024 + n0 + n8] = P.v4;
  }
}

// ---------------------------------------------------------------------------
// MFMA flash attention (fp16), LDS-staged + double-buffered K/V tiles.
// QBLK=64 (4 waves x 16 q-rows), KBLK=64. Tiles [64][64] fp16, XOR-swizzled
// (pre-swizzled global src -> linear gld_lds dest -> swizzled ds_read).
// One __syncthreads per tile (2-phase: stage t+1, compute t, barrier).
// LDS: 2x8KB K + 2x8KB V + 11KB P = 43.3KB -> 3 blocks/CU.
// ---------------------------------------------------------------------------
__device__ __forceinline__ void stage_tile64(const u16* __restrict__ src,
                                             u16* __restrict__ lds, int t,
                                             int rowbase, size_t stride,
                                             int colbase) {
#pragma unroll
  for (int u = 0; u < 2; ++u) {
    int idx = u * 256 + t;
    int row = idx >> 3;
    int cs = (idx & 7) ^ (row & 7);  // inverse-swizzled source chunk
    gld_lds16(src + (size_t)(rowbase + row) * stride + colbase + cs * 8,
              lds + (size_t)(u * 256 + (t >> 6) * 64) * 8);
  }
}

__global__ __launch_bounds__(256) void flash_f16(
    const u16* __restrict__ q, const u16* __restrict__ k,
    const u16* __restrict__ vt, u16* __restrict__ ao_hi,
    u16* __restrict__ ao_lo) {
  __shared__ __align__(16) u16 sK[2][4096];
  __shared__ __align__(16) u16 sV[2][4096];
  __shared__ __align__(16) u16 sP[4][16][88];  // [wave][row][col pad]
  const int t = threadIdx.x;
  const int wv = t >> 6, lane = t & 63;
  const int fr = lane & 15;   // A-frag row / D col
  const int g = lane >> 4;    // k-chunk group; D rows g*4+r
  // Bijective XCD-chunk swizzle: 2048 blocks = 8 xcd x 256.
  int flat = blockIdx.x;
  int nf = (flat & 7) * 256 + (flat >> 3);
  const int qb = nf & 15, bh = nf >> 4;
  const int q0 = qb * 64;
  const int b = bh >> 4, h = bh & 15;

  const u16* qrow = q + ((size_t)(b * 1024 + q0 + wv * 16 + fr)) * 1024 + h * 64;
  const u16* krow = k + ((size_t)b * 1024) * 1024 + h * 64;
  const u16* vbase = vt + (size_t)bh * 64 * 1024;

  // Q fragments: one-time per-lane global read (scattered, but once)
  f16x8 aQ[2];
#pragma unroll
  for (int c = 0; c < 2; ++c)
    aQ[c] = *(const f16x8*)&qrow[c * 32 + g * 8];

  float m_run[4], l_run[4];
  float4_t o[4];
  const float4_t zero = {0.f, 0.f, 0.f, 0.f};
#pragma unroll
  for (int r = 0; r < 4; ++r) { m_run[r] = -1e30f; l_run[r] = 0.f; }
#pragma unroll
  for (int dt = 0; dt < 4; ++dt) o[dt] = zero;
  const float scale = 0.125f;

  // Prologue: stage tile 0 into buffer 0
  stage_tile64(krow, &sK[0][0], t, 0, 1024, 0);
  stage_tile64(vbase, &sV[0][0], t, 0, 1024, 0);
  __syncthreads();

  int cur = 0;
  for (int it = 0; it < 16; ++it) {
    const int k0 = it * 64;
    // Issue next-tile stage first (latency hides under compute below)
    if (it < 15) {
      stage_tile64(krow, &sK[cur ^ 1][0], t, k0 + 64, 1024, 0);
      stage_tile64(vbase, &sV[cur ^ 1][0], t, 0, 1024, k0 + 64);
    }
    const u16* sKc = &sK[cur][0];
    const u16* sVc = &sV[cur][0];

    // QK^T: 8 MFMA, B-frags from swizzled LDS (conflict-free ds_read_b128)
    float4_t sac[4];
#pragma unroll
    for (int j = 0; j < 4; ++j) sac[j] = zero;
#pragma unroll
    for (int j = 0; j < 4; ++j) {
      f16x8 kb0 = *(const f16x8*)&sKc[elem_off(j * 16 + fr, g * 8)];
      f16x8 kb1 = *(const f16x8*)&sKc[elem_off(j * 16 + fr, 32 + g * 8)];
      __builtin_amdgcn_s_setprio(1);
      sac[j] = __builtin_amdgcn_mfma_f32_16x16x32_f16(aQ[0], kb0, sac[j], 0, 0, 0);
      sac[j] = __builtin_amdgcn_mfma_f32_16x16x32_f16(aQ[1], kb1, sac[j], 0, 0, 0);
      __builtin_amdgcn_s_setprio(0);
    }

    // Online softmax; lane's S rows are g*4+r, col j*16+fr
    float corr[4];
#pragma unroll
    for (int r = 0; r < 4; ++r) {
      float p0 = sac[0][r] * scale, p1 = sac[1][r] * scale;
      float p2 = sac[2][r] * scale, p3 = sac[3][r] * scale;
      float mx = fmaxf(fmaxf(p0, p1), fmaxf(p2, p3));
#pragma unroll
      for (int mask = 8; mask >= 1; mask >>= 1)
        mx = fmaxf(mx, __shfl_xor(mx, mask));
      float m_new = fmaxf(m_run[r], mx);
      corr[r] = __expf(m_run[r] - m_new);
      p0 = __expf(p0 - m_new); p1 = __expf(p1 - m_new);
      p2 = __expf(p2 - m_new); p3 = __expf(p3 - m_new);
      float rs = p0 + p1 + p2 + p3;
#pragma unroll
      for (int mask = 8; mask >= 1; mask >>= 1) rs += __shfl_xor(rs, mask);
      l_run[r] = fmaf(l_run[r], corr[r], rs);
      m_run[r] = m_new;
      int row = g * 4 + r;
      sP[wv][row][0 * 16 + fr] = f16_bits(p0);
      sP[wv][row][1 * 16 + fr] = f16_bits(p1);
      sP[wv][row][2 * 16 + fr] = f16_bits(p2);
      sP[wv][row][3 * 16 + fr] = f16_bits(p3);
    }

    // Rescale O (skip when every corr==1 -> exact identity)
    bool noscale = (corr[0] == 1.f) & (corr[1] == 1.f) &
                   (corr[2] == 1.f) & (corr[3] == 1.f);
    if (!__all(noscale)) {
#pragma unroll
      for (int dt = 0; dt < 4; ++dt)
#pragma unroll
        for (int r = 0; r < 4; ++r) o[dt][r] *= corr[r];
    }

    // PV: A-frags from wave-local sP (intra-wave dep), B from swizzled sV
    f16x8 pa[2];
#pragma unroll
    for (int c = 0; c < 2; ++c)
      pa[c] = *(const f16x8*)&sP[wv][fr][c * 32 + g * 8];
#pragma unroll
    for (int dt = 0; dt < 4; ++dt) {
      f16x8 vb0 = *(const f16x8*)&sVc[elem_off(dt * 16 + fr, g * 8)];
      f16x8 vb1 = *(const f16x8*)&sVc[elem_off(dt * 16 + fr, 32 + g * 8)];
      __builtin_amdgcn_s_setprio(1);
      o[dt] = __builtin_amdgcn_mfma_f32_16x16x32_f16(pa[0], vb0, o[dt], 0, 0, 0);
      o[dt] = __builtin_amdgcn_mfma_f32_16x16x32_f16(pa[1], vb1, o[dt], 0, 0, 0);
      __builtin_amdgcn_s_setprio(0);
    }

    // Drain stage (vmcnt0+lgkm0 implied) -> next tile ready; swap buffers
    __syncthreads();
    cur ^= 1;
  }

  // Epilogue: normalize, split bf16 hi/lo for the split proj GEMM
#pragma unroll
  for (int r = 0; r < 4; ++r) {
    float inv = 1.0f / l_run[r];
    int qg = q0 + wv * 16 + g * 4 + r;
#pragma unroll
    for (int dt = 0; dt < 4; ++dt) {
      float v = o[dt][r] * inv;
      u16 hb = f32_to_bf16(v);
      size_t off = ((size_t)(b * 1024 + qg)) * 1024 + h * 64 + dt * 16 + fr;
      ao_hi[off] = hb;
      ao_lo[off] = f32_to_bf16(v - bf16_to_f32(hb));
    }
  }
}

// ---------------------------------------------------------------------------
extern "C" void kernel_launch(void* const* d_in, const int* in_sizes, int n_in,
                              void* d_out, int out_size, void* d_ws, size_t ws_size,
                              hipStream_t stream) {
  const float* x      = (const float*)d_in[0];
  const float* w_qkv  = (const float*)d_in[1];
  const float* b_qkv  = (const float*)d_in[2];
  const float* qn_w   = (const float*)d_in[3];
  const float* kn_w   = (const float*)d_in[4];
  const float* w_proj = (const float*)d_in[5];
  const float* b_proj = (const float*)d_in[6];
  float* out = (float*)d_out;

  // ws layout, all u16 (~144 MB)
  u16* x_hi  = (u16*)d_ws;          // 8192*1024
  u16* x_lo  = x_hi + 8388608;
  u16* wq_hi = x_lo + 8388608;      // 3072*1024
  u16* wq_lo = wq_hi + 3145728;
  u16* wp_hi = wq_lo + 3145728;     // 1024*1024
  u16* wp_lo = wp_hi + 1048576;
  u16* qb    = wp_lo + 1048576;     // fp16 q [8192][1024]
  u16* kb    = qb + 8388608;        // fp16 k
  u16* vb    = kb + 8388608;        // fp16 v
  u16* vtb   = vb + 8388608;        // fp16 v^T [128][64][1024]
  u16* ao_hi = vtb + 8388608;       // bf16 attn-out hi
  u16* ao_lo = ao_hi + 8388608;     // bf16 attn-out lo

  split_bf16<<<8192, 256, 0, stream>>>(x, x_hi, x_lo);
  split_bf16<<<3072, 256, 0, stream>>>(w_qkv, wq_hi, wq_lo);
  split_bf16<<<1024, 256, 0, stream>>>(w_proj, wp_hi, wp_lo);

  // QKV projection (split-bf16, fp32-grade) + fused RMSNorm -> fp16 q,k,v
  gemm_split<0><<<dim3(QKV_N / 128, M_ROWS / 128), 256, 0, stream>>>(
      x_hi, x_lo, wq_hi, wq_lo, b_qkv, qb, kb, vb, qn_w, kn_w,
      M_ROWS, QKV_N, C_DIM);

  vtrans16<<<dim3(16, 128), 256, 0, stream>>>(vb, vtb);

  flash_f16<<<2048, 256, 0, stream>>>(qb, kb, vtb, ao_hi, ao_lo);

  // Output projection (split-bf16) -> fp32 out
  gemm_split<1><<<dim3(C_DIM / 128, M_ROWS / 128), 256, 0, stream>>>(
      ao_hi, ao_lo, wp_hi, wp_lo, b_proj, out, nullptr, nullptr,
      nullptr, nullptr, M_ROWS, C_DIM, C_DIM);
}

// Round 11
// 403.731 us; speedup vs baseline: 1.4077x; 1.1110x over previous
//
#include <hip/hip_runtime.h>
#include <hip/hip_bf16.h>
#include <stdint.h>

// Problem constants: B=8, N=1024, C=1024, H=16, D=64, M=B*N=8192
#define M_ROWS 8192
#define C_DIM  1024
#define QKV_N  3072

typedef _Float16 f16;
typedef __attribute__((ext_vector_type(8))) _Float16 f16x8;   // 4 VGPRs
typedef __attribute__((ext_vector_type(8))) short short8_t;   // 8 bf16
typedef __attribute__((ext_vector_type(4))) float float4_t;   // 4 fp32 acc
typedef unsigned short u16;
typedef unsigned int u32;

__device__ __forceinline__ u16 f16_bits(float x) {
  union { f16 h; u16 u; } c; c.h = (f16)x; return c.u;
}
__device__ __forceinline__ u16 f32_to_bf16(float f) {
  u32 u = __float_as_uint(f);
  u32 r = (u + 0x7fffu + ((u >> 16) & 1u)) >> 16;  // RNE
  return (u16)r;
}
__device__ __forceinline__ float bf16_to_f32(u16 h) {
  return __uint_as_float((u32)h << 16);
}
__device__ __forceinline__ void gld_lds16(const void* g, void* l) {
  __builtin_amdgcn_global_load_lds(
      (const __attribute__((address_space(1))) u32*)g,
      (__attribute__((address_space(3))) u32*)l, 16, 0, 0);
}
// Swizzled elem offset in a [64][64]-fp16 LDS tile (row len 128B):
// byte ^= ((row&7)<<4)  <=>  elem ^= ((row&7)<<3)
__device__ __forceinline__ int elem_off(int row, int e0) {
  return row * 64 + (e0 ^ ((row & 7) << 3));
}

// ---------------------------------------------------------------------------
// split fp32 -> (hi, lo) bf16 pair; 4 elems/thread
// ---------------------------------------------------------------------------
__global__ __launch_bounds__(256) void split_bf16(
    const float* __restrict__ in, u16* __restrict__ hi, u16* __restrict__ lo) {
  int i = blockIdx.x * 256 + threadIdx.x;
  float4 v = ((const float4*)in)[i];
  float x[4] = {v.x, v.y, v.z, v.w};
  union { u16 u[4]; uint2 v2; } H, L;
#pragma unroll
  for (int j = 0; j < 4; ++j) {
    u16 h = f32_to_bf16(x[j]);
    H.u[j] = h;
    L.u[j] = f32_to_bf16(x[j] - bf16_to_f32(h));
  }
  ((uint2*)hi)[i] = H.v2;
  ((uint2*)lo)[i] = L.v2;
}

// ---------------------------------------------------------------------------
// Split-bf16 MFMA GEMM (Ah+Al)@(Bh+Bl)^T + bias, drops Al*Bl (fp32-grade).
// 128x128 tile, BK=32, 256 thr (4 waves 2x2), 16x16x32_bf16, m97 structure.
// MODE 0: QKV — fused per-head RMSNorm on sections 0,1; writes fp16 q,k,v.
// MODE 1: proj — fp32 + bias to O0 (the final output).
// ---------------------------------------------------------------------------
template <int MODE>
__global__ __launch_bounds__(256) void gemm_split(
    const u16* __restrict__ Ah, const u16* __restrict__ Al,
    const u16* __restrict__ Bh, const u16* __restrict__ Bl,
    const float* __restrict__ bias, void* __restrict__ O0,
    void* __restrict__ O1, void* __restrict__ O2,
    const float* __restrict__ qn_w, const float* __restrict__ kn_w,
    int M, int N, int K) {
  __shared__ u16 sAh[128 * 32], sAl[128 * 32], sBh[128 * 32], sBl[128 * 32];
  const int t = threadIdx.x;
  const int wv = t >> 6;
  const int lane = t & 63;
  const int n0 = blockIdx.x * 128;
  const int m0 = blockIdx.y * 128;
  const int wm = wv >> 1, wn = wv & 1;
  const int fr = lane & 15;
  const int g = lane >> 4;
  const int kfr = g * 8;

  float4_t acc[4][4];
  const float4_t zero = {0.f, 0.f, 0.f, 0.f};
#pragma unroll
  for (int i = 0; i < 4; ++i)
#pragma unroll
    for (int j = 0; j < 4; ++j) acc[i][j] = zero;

  for (int k0 = 0; k0 < K; k0 += 32) {
#pragma unroll
    for (int u = 0; u < 2; ++u) {
      int idx = u * 256 + t;
      int row = idx >> 2;
      int ke = (idx & 3) * 8;
      int ldsoff = (u * 256 + wv * 64) * 8;  // wave-uniform base (elems)
      const size_t ga = (size_t)(m0 + row) * K + k0 + ke;
      const size_t gb = (size_t)(n0 + row) * K + k0 + ke;
      gld_lds16(Ah + ga, sAh + ldsoff);
      gld_lds16(Al + ga, sAl + ldsoff);
      gld_lds16(Bh + gb, sBh + ldsoff);
      gld_lds16(Bl + gb, sBl + ldsoff);
    }
    __syncthreads();

    short8_t ah[4], al[4], bh[4], bl[4];
#pragma unroll
    for (int i = 0; i < 4; ++i) {
      ah[i] = *(const short8_t*)&sAh[(wm * 64 + i * 16 + fr) * 32 + kfr];
      al[i] = *(const short8_t*)&sAl[(wm * 64 + i * 16 + fr) * 32 + kfr];
      bh[i] = *(const short8_t*)&sBh[(wn * 64 + i * 16 + fr) * 32 + kfr];
      bl[i] = *(const short8_t*)&sBl[(wn * 64 + i * 16 + fr) * 32 + kfr];
    }
#pragma unroll
    for (int i = 0; i < 4; ++i)
#pragma unroll
      for (int j = 0; j < 4; ++j) {
        acc[i][j] = __builtin_amdgcn_mfma_f32_16x16x32_bf16(ah[i], bh[j], acc[i][j], 0, 0, 0);
        acc[i][j] = __builtin_amdgcn_mfma_f32_16x16x32_bf16(ah[i], bl[j], acc[i][j], 0, 0, 0);
        acc[i][j] = __builtin_amdgcn_mfma_f32_16x16x32_bf16(al[i], bh[j], acc[i][j], 0, 0, 0);
      }
    __syncthreads();
  }

  // Epilogue. C/D layout: col=lane&15, row=(lane>>4)*4+reg.
  const int r0 = g * 4;
  const int nw = n0 + wn * 64;  // wave col base; 64-aligned -> exactly 1 head
  float bz[4];
#pragma unroll
  for (int j = 0; j < 4; ++j) bz[j] = bias[nw + j * 16 + fr];

  if (MODE == 0) {
    const int sec = nw >> 10;           // 0=q 1=k 2=v
    const int h = (nw >> 6) & 15;
    u16* O = (sec == 0) ? (u16*)O0 : ((sec == 1) ? (u16*)O1 : (u16*)O2);
    float wn_[4];
    if (sec < 2) {
      const float* wvec = (sec == 0) ? qn_w : kn_w;
#pragma unroll
      for (int j = 0; j < 4; ++j) wn_[j] = wvec[j * 16 + fr];
    }
#pragma unroll
    for (int i = 0; i < 4; ++i) {
      float val[4][4];  // [j][r]
#pragma unroll
      for (int j = 0; j < 4; ++j)
#pragma unroll
        for (int r = 0; r < 4; ++r) val[j][r] = acc[i][j][r] + bz[j];
      if (sec < 2) {
        // RMS over the head's 64 cols: 4 j-regs x 16 fr-lanes (same g, same r)
#pragma unroll
        for (int r = 0; r < 4; ++r) {
          float ss = 0.f;
#pragma unroll
          for (int j = 0; j < 4; ++j) ss += val[j][r] * val[j][r];
#pragma unroll
          for (int mask = 8; mask >= 1; mask >>= 1) ss += __shfl_xor(ss, mask);
          float sc = rsqrtf(ss * (1.0f / 64.0f) + 1e-6f);
#pragma unroll
          for (int j = 0; j < 4; ++j) val[j][r] *= sc * wn_[j];
        }
      }
#pragma unroll
      for (int j = 0; j < 4; ++j) {
        int col = h * 64 + j * 16 + fr;
#pragma unroll
        for (int r = 0; r < 4; ++r) {
          int m = m0 + wm * 64 + i * 16 + r0 + r;
          O[(size_t)m * 1024 + col] = f16_bits(val[j][r]);
        }
      }
    }
  } else {
    float* O = (float*)O0;
#pragma unroll
    for (int j = 0; j < 4; ++j) {
      int n = nw + j * 16 + fr;
#pragma unroll
      for (int i = 0; i < 4; ++i) {
        int mb = m0 + wm * 64 + i * 16 + r0;
#pragma unroll
        for (int r = 0; r < 4; ++r)
          O[(size_t)(mb + r) * 1024 + n] = acc[i][j][r] + bz[j];
      }
    }
  }
}

// ---------------------------------------------------------------------------
// V transpose: v fp16 [8192][1024] -> vt fp16 [bh=128][d=64][n=1024]
// ---------------------------------------------------------------------------
__global__ __launch_bounds__(256) void vtrans16(const u16* __restrict__ v,
                                                u16* __restrict__ vt) {
  __shared__ __align__(16) u16 T[64][80];
  const int t = threadIdx.x;
  const int nb = blockIdx.x;   // 16 n-tiles
  const int bh = blockIdx.y;   // 128
  const int b = bh >> 4, h = bh & 15;
  const int n0 = nb * 64;
#pragma unroll
  for (int u = 0; u < 2; ++u) {
    int idx = u * 256 + t;       // 0..511
    int row = idx >> 3;          // n 0..63
    int c8 = (idx & 7) * 8;      // d chunk
    uint4 val = *(const uint4*)&v[((size_t)(b * 1024 + n0 + row)) * 1024 + h * 64 + c8];
    *(uint4*)&T[row][c8] = val;
  }
  __syncthreads();
#pragma unroll
  for (int u = 0; u < 2; ++u) {
    int idx = u * 256 + t;
    int d = idx >> 3;            // 0..63
    int n8 = (idx & 7) * 8;
    union { u16 q[8]; uint4 v4; } P;
#pragma unroll
    for (int i = 0; i < 8; ++i) P.q[i] = T[n8 + i][d];
    *(uint4*)&vt[((size_t)bh * 64 + d) * 1024 + n0 + n8] = P.v4;
  }
}

// ---------------------------------------------------------------------------
// MFMA flash attention (fp16), LDS-staged + double-buffered K/V, SWAPPED
// QK^T (mfma(K,Q) -> S^T): each lane owns ONE q-row's 16 S-values, so the
// softmax row-reduce is 15 local ops + 2 shfl_xor (vs 32 butterfly shuffles).
// QBLK=64 (4 waves x 16 q-rows), KBLK=64, XOR-swizzled K/V tiles.
// ---------------------------------------------------------------------------
__device__ __forceinline__ void stage_tile64(const u16* __restrict__ src,
                                             u16* __restrict__ lds, int t,
                                             int rowbase, size_t stride,
                                             int colbase) {
#pragma unroll
  for (int u = 0; u < 2; ++u) {
    int idx = u * 256 + t;
    int row = idx >> 3;
    int cs = (idx & 7) ^ (row & 7);  // inverse-swizzled source chunk
    gld_lds16(src + (size_t)(rowbase + row) * stride + colbase + cs * 8,
              lds + (size_t)(u * 256 + (t >> 6) * 64) * 8);
  }
}

__global__ __launch_bounds__(256) void flash_f16(
    const u16* __restrict__ q, const u16* __restrict__ k,
    const u16* __restrict__ vt, u16* __restrict__ ao_hi,
    u16* __restrict__ ao_lo) {
  __shared__ __align__(16) u16 sK[2][4096];
  __shared__ __align__(16) u16 sV[2][4096];
  __shared__ __align__(16) u16 sP[4][16][88];  // [wave][q-row][k col, pad]
  const int t = threadIdx.x;
  const int wv = t >> 6, lane = t & 63;
  const int fr = lane & 15;   // frag row; q-row for softmax (S^T col)
  const int g = lane >> 4;    // k-chunk group
  // Bijective XCD-chunk swizzle: 2048 blocks = 8 xcd x 256.
  int flat = blockIdx.x;
  int nf = (flat & 7) * 256 + (flat >> 3);
  const int qb = nf & 15, bh = nf >> 4;
  const int q0 = qb * 64;
  const int b = bh >> 4, h = bh & 15;

  const u16* qrow = q + ((size_t)(b * 1024 + q0 + wv * 16 + fr)) * 1024 + h * 64;
  const u16* krow = k + ((size_t)b * 1024) * 1024 + h * 64;
  const u16* vbase = vt + (size_t)bh * 64 * 1024;

  // Q fragments: one-time per-lane global read; serves as MFMA B-operand
  // (B[k=d][col=q-row]) — identical lane mapping to the old A-operand use.
  f16x8 aQ[2];
#pragma unroll
  for (int c = 0; c < 2; ++c)
    aQ[c] = *(const f16x8*)&qrow[c * 32 + g * 8];

  float m_run = -1e30f, l_run = 0.f;  // per-lane: stats of q-row `fr`
  float4_t o[4];
  const float4_t zero = {0.f, 0.f, 0.f, 0.f};
#pragma unroll
  for (int dt = 0; dt < 4; ++dt) o[dt] = zero;
  const float scale = 0.125f;

  // Prologue: stage tile 0 into buffer 0
  stage_tile64(krow, &sK[0][0], t, 0, 1024, 0);
  stage_tile64(vbase, &sV[0][0], t, 0, 1024, 0);
  __syncthreads();

  int cur = 0;
  for (int it = 0; it < 16; ++it) {
    const int k0 = it * 64;
    // Issue next-tile stage first (latency hides under compute below)
    if (it < 15) {
      stage_tile64(krow, &sK[cur ^ 1][0], t, k0 + 64, 1024, 0);
      stage_tile64(vbase, &sV[cur ^ 1][0], t, 0, 1024, k0 + 64);
    }
    const u16* sKc = &sK[cur][0];
    const u16* sVc = &sV[cur][0];

    // Swapped QK^T: sac[j] = S^T tile; lane reg r = S[q=fr][k0+j*16+g*4+r]
    float4_t sac[4];
#pragma unroll
    for (int j = 0; j < 4; ++j) sac[j] = zero;
#pragma unroll
    for (int j = 0; j < 4; ++j) {
      f16x8 kb0 = *(const f16x8*)&sKc[elem_off(j * 16 + fr, g * 8)];
      f16x8 kb1 = *(const f16x8*)&sKc[elem_off(j * 16 + fr, 32 + g * 8)];
      __builtin_amdgcn_s_setprio(1);
      sac[j] = __builtin_amdgcn_mfma_f32_16x16x32_f16(kb0, aQ[0], sac[j], 0, 0, 0);
      sac[j] = __builtin_amdgcn_mfma_f32_16x16x32_f16(kb1, aQ[1], sac[j], 0, 0, 0);
      __builtin_amdgcn_s_setprio(0);
    }

    // Lane-local softmax over the 16 held S-values; cross-lane only over
    // the 4 g-groups holding the same q-row (xor 16, 32).
    float sv[4][4];
    float pmax = -1e30f;
#pragma unroll
    for (int j = 0; j < 4; ++j)
#pragma unroll
      for (int r = 0; r < 4; ++r) {
        sv[j][r] = sac[j][r] * scale;
        pmax = fmaxf(pmax, sv[j][r]);
      }
    pmax = fmaxf(pmax, __shfl_xor(pmax, 16));
    pmax = fmaxf(pmax, __shfl_xor(pmax, 32));
    float m_new = fmaxf(m_run, pmax);
    float corr = __expf(m_run - m_new);
    float rs = 0.f;
#pragma unroll
    for (int j = 0; j < 4; ++j) {
      union { u16 u[4]; uint2 v2; } P;
#pragma unroll
      for (int r = 0; r < 4; ++r) {
        float p = __expf(sv[j][r] - m_new);
        rs += p;
        P.u[r] = f16_bits(p);
      }
      // lane's 4 consecutive k-slots j*16+g*4.. -> one 8B store
      *(uint2*)&sP[wv][fr][j * 16 + g * 4] = P.v2;
    }
    rs += __shfl_xor(rs, 16);
    rs += __shfl_xor(rs, 32);
    l_run = fmaf(l_run, corr, rs);
    m_run = m_new;

    // Rescale O: rows of o are q = g*4+r -> broadcast corr from lane
    // (own 16-group, fr = g*4+r).
#pragma unroll
    for (int r = 0; r < 4; ++r) {
      float cr = __shfl(corr, (lane & 48) + ((lane >> 4) << 2) + r);
#pragma unroll
      for (int dt = 0; dt < 4; ++dt) o[dt][r] *= cr;
    }

    // PV: A-frags from wave-local sP (intra-wave dep), B from swizzled sV
    f16x8 pa[2];
#pragma unroll
    for (int c = 0; c < 2; ++c)
      pa[c] = *(const f16x8*)&sP[wv][fr][c * 32 + g * 8];
#pragma unroll
    for (int dt = 0; dt < 4; ++dt) {
      f16x8 vb0 = *(const f16x8*)&sVc[elem_off(dt * 16 + fr, g * 8)];
      f16x8 vb1 = *(const f16x8*)&sVc[elem_off(dt * 16 + fr, 32 + g * 8)];
      __builtin_amdgcn_s_setprio(1);
      o[dt] = __builtin_amdgcn_mfma_f32_16x16x32_f16(pa[0], vb0, o[dt], 0, 0, 0);
      o[dt] = __builtin_amdgcn_mfma_f32_16x16x32_f16(pa[1], vb1, o[dt], 0, 0, 0);
      __builtin_amdgcn_s_setprio(0);
    }

    // Drain stage -> next tile ready; swap buffers
    __syncthreads();
    cur ^= 1;
  }

  // Epilogue: normalize (l for row g*4+r broadcast from its owner lane),
  // split bf16 hi/lo for the split proj GEMM.
#pragma unroll
  for (int r = 0; r < 4; ++r) {
    float lq = __shfl(l_run, (lane & 48) + ((lane >> 4) << 2) + r);
    float inv = 1.0f / lq;
    int qg = q0 + wv * 16 + g * 4 + r;
#pragma unroll
    for (int dt = 0; dt < 4; ++dt) {
      float v = o[dt][r] * inv;
      u16 hb = f32_to_bf16(v);
      size_t off = ((size_t)(b * 1024 + qg)) * 1024 + h * 64 + dt * 16 + fr;
      ao_hi[off] = hb;
      ao_lo[off] = f32_to_bf16(v - bf16_to_f32(hb));
    }
  }
}

// ---------------------------------------------------------------------------
extern "C" void kernel_launch(void* const* d_in, const int* in_sizes, int n_in,
                              void* d_out, int out_size, void* d_ws, size_t ws_size,
                              hipStream_t stream) {
  const float* x      = (const float*)d_in[0];
  const float* w_qkv  = (const float*)d_in[1];
  const float* b_qkv  = (const float*)d_in[2];
  const float* qn_w   = (const float*)d_in[3];
  const float* kn_w   = (const float*)d_in[4];
  const float* w_proj = (const float*)d_in[5];
  const float* b_proj = (const float*)d_in[6];
  float* out = (float*)d_out;

  // ws layout, all u16 (~144 MB)
  u16* x_hi  = (u16*)d_ws;          // 8192*1024
  u16* x_lo  = x_hi + 8388608;
  u16* wq_hi = x_lo + 8388608;      // 3072*1024
  u16* wq_lo = wq_hi + 3145728;
  u16* wp_hi = wq_lo + 3145728;     // 1024*1024
  u16* wp_lo = wp_hi + 1048576;
  u16* qb    = wp_lo + 1048576;     // fp16 q [8192][1024]
  u16* kb    = qb + 8388608;        // fp16 k
  u16* vb    = kb + 8388608;        // fp16 v
  u16* vtb   = vb + 8388608;        // fp16 v^T [128][64][1024]
  u16* ao_hi = vtb + 8388608;       // bf16 attn-out hi
  u16* ao_lo = ao_hi + 8388608;     // bf16 attn-out lo

  split_bf16<<<8192, 256, 0, stream>>>(x, x_hi, x_lo);
  split_bf16<<<3072, 256, 0, stream>>>(w_qkv, wq_hi, wq_lo);
  split_bf16<<<1024, 256, 0, stream>>>(w_proj, wp_hi, wp_lo);

  // QKV projection (split-bf16, fp32-grade) + fused RMSNorm -> fp16 q,k,v
  gemm_split<0><<<dim3(QKV_N / 128, M_ROWS / 128), 256, 0, stream>>>(
      x_hi, x_lo, wq_hi, wq_lo, b_qkv, qb, kb, vb, qn_w, kn_w,
      M_ROWS, QKV_N, C_DIM);

  vtrans16<<<dim3(16, 128), 256, 0, stream>>>(vb, vtb);

  flash_f16<<<2048, 256, 0, stream>>>(qb, kb, vtb, ao_hi, ao_lo);

  // Output projection (split-bf16) -> fp32 out
  gemm_split<1><<<dim3(C_DIM / 128, M_ROWS / 128), 256, 0, stream>>>(
      ao_hi, ao_lo, wp_hi, wp_lo, b_proj, out, nullptr, nullptr,
      nullptr, nullptr, M_ROWS, C_DIM, C_DIM);
}

// Round 12
// 401.608 us; speedup vs baseline: 1.4152x; 1.0053x over previous
//
#include <hip/hip_runtime.h>
#include <hip/hip_bf16.h>
#include <stdint.h>

// Problem constants: B=8, N=1024, C=1024, H=16, D=64, M=B*N=8192
#define M_ROWS 8192
#define C_DIM  1024
#define QKV_N  3072

typedef _Float16 f16;
typedef __attribute__((ext_vector_type(8))) _Float16 f16x8;   // 4 VGPRs
typedef __attribute__((ext_vector_type(8))) short short8_t;   // 8 bf16
typedef __attribute__((ext_vector_type(4))) float float4_t;   // 4 fp32 acc
typedef unsigned short u16;
typedef unsigned int u32;

__device__ __forceinline__ u16 f16_bits(float x) {
  union { f16 h; u16 u; } c; c.h = (f16)x; return c.u;
}
__device__ __forceinline__ u16 f32_to_bf16(float f) {
  u32 u = __float_as_uint(f);
  u32 r = (u + 0x7fffu + ((u >> 16) & 1u)) >> 16;  // RNE
  return (u16)r;
}
__device__ __forceinline__ float bf16_to_f32(u16 h) {
  return __uint_as_float((u32)h << 16);
}
__device__ __forceinline__ void gld_lds16(const void* g, void* l) {
  __builtin_amdgcn_global_load_lds(
      (const __attribute__((address_space(1))) u32*)g,
      (__attribute__((address_space(3))) u32*)l, 16, 0, 0);
}
// Swizzled elem offset in a [64][64]-fp16 LDS tile (row len 128B):
// byte ^= ((row&7)<<4)  <=>  elem ^= ((row&7)<<3)
__device__ __forceinline__ int elem_off(int row, int e0) {
  return row * 64 + (e0 ^ ((row & 7) << 3));
}

// ---------------------------------------------------------------------------
// split fp32 -> (hi, lo) bf16 pair; 4 elems/thread
// ---------------------------------------------------------------------------
__global__ __launch_bounds__(256) void split_bf16(
    const float* __restrict__ in, u16* __restrict__ hi, u16* __restrict__ lo) {
  int i = blockIdx.x * 256 + threadIdx.x;
  float4 v = ((const float4*)in)[i];
  float x[4] = {v.x, v.y, v.z, v.w};
  union { u16 u[4]; uint2 v2; } H, L;
#pragma unroll
  for (int j = 0; j < 4; ++j) {
    u16 h = f32_to_bf16(x[j]);
    H.u[j] = h;
    L.u[j] = f32_to_bf16(x[j] - bf16_to_f32(h));
  }
  ((uint2*)hi)[i] = H.v2;
  ((uint2*)lo)[i] = L.v2;
}

// ---------------------------------------------------------------------------
// Split-bf16 MFMA GEMM (Ah+Al)@(Bh+Bl)^T + bias, drops Al*Bl (fp32-grade).
// 128x128 tile, BK=32, 256 thr (4 waves 2x2), 16x16x32_bf16, m97 structure.
// MODE 0: QKV — fused per-head RMSNorm on sections 0,1; writes fp16 q,k,v.
// MODE 1: proj — fp32 + bias to O0 (the final output).
// ---------------------------------------------------------------------------
template <int MODE>
__global__ __launch_bounds__(256) void gemm_split(
    const u16* __restrict__ Ah, const u16* __restrict__ Al,
    const u16* __restrict__ Bh, const u16* __restrict__ Bl,
    const float* __restrict__ bias, void* __restrict__ O0,
    void* __restrict__ O1, void* __restrict__ O2,
    const float* __restrict__ qn_w, const float* __restrict__ kn_w,
    int M, int N, int K) {
  __shared__ u16 sAh[128 * 32], sAl[128 * 32], sBh[128 * 32], sBl[128 * 32];
  const int t = threadIdx.x;
  const int wv = t >> 6;
  const int lane = t & 63;
  const int n0 = blockIdx.x * 128;
  const int m0 = blockIdx.y * 128;
  const int wm = wv >> 1, wn = wv & 1;
  const int fr = lane & 15;
  const int g = lane >> 4;
  const int kfr = g * 8;

  float4_t acc[4][4];
  const float4_t zero = {0.f, 0.f, 0.f, 0.f};
#pragma unroll
  for (int i = 0; i < 4; ++i)
#pragma unroll
    for (int j = 0; j < 4; ++j) acc[i][j] = zero;

  for (int k0 = 0; k0 < K; k0 += 32) {
#pragma unroll
    for (int u = 0; u < 2; ++u) {
      int idx = u * 256 + t;
      int row = idx >> 2;
      int ke = (idx & 3) * 8;
      int ldsoff = (u * 256 + wv * 64) * 8;  // wave-uniform base (elems)
      const size_t ga = (size_t)(m0 + row) * K + k0 + ke;
      const size_t gb = (size_t)(n0 + row) * K + k0 + ke;
      gld_lds16(Ah + ga, sAh + ldsoff);
      gld_lds16(Al + ga, sAl + ldsoff);
      gld_lds16(Bh + gb, sBh + ldsoff);
      gld_lds16(Bl + gb, sBl + ldsoff);
    }
    __syncthreads();

    short8_t ah[4], al[4], bh[4], bl[4];
#pragma unroll
    for (int i = 0; i < 4; ++i) {
      ah[i] = *(const short8_t*)&sAh[(wm * 64 + i * 16 + fr) * 32 + kfr];
      al[i] = *(const short8_t*)&sAl[(wm * 64 + i * 16 + fr) * 32 + kfr];
      bh[i] = *(const short8_t*)&sBh[(wn * 64 + i * 16 + fr) * 32 + kfr];
      bl[i] = *(const short8_t*)&sBl[(wn * 64 + i * 16 + fr) * 32 + kfr];
    }
#pragma unroll
    for (int i = 0; i < 4; ++i)
#pragma unroll
      for (int j = 0; j < 4; ++j) {
        acc[i][j] = __builtin_amdgcn_mfma_f32_16x16x32_bf16(ah[i], bh[j], acc[i][j], 0, 0, 0);
        acc[i][j] = __builtin_amdgcn_mfma_f32_16x16x32_bf16(ah[i], bl[j], acc[i][j], 0, 0, 0);
        acc[i][j] = __builtin_amdgcn_mfma_f32_16x16x32_bf16(al[i], bh[j], acc[i][j], 0, 0, 0);
      }
    __syncthreads();
  }

  // Epilogue. C/D layout: col=lane&15, row=(lane>>4)*4+reg.
  const int r0 = g * 4;
  const int nw = n0 + wn * 64;  // wave col base; 64-aligned -> exactly 1 head
  float bz[4];
#pragma unroll
  for (int j = 0; j < 4; ++j) bz[j] = bias[nw + j * 16 + fr];

  if (MODE == 0) {
    const int sec = nw >> 10;           // 0=q 1=k 2=v
    const int h = (nw >> 6) & 15;
    u16* O = (sec == 0) ? (u16*)O0 : ((sec == 1) ? (u16*)O1 : (u16*)O2);
    float wn_[4];
    if (sec < 2) {
      const float* wvec = (sec == 0) ? qn_w : kn_w;
#pragma unroll
      for (int j = 0; j < 4; ++j) wn_[j] = wvec[j * 16 + fr];
    }
#pragma unroll
    for (int i = 0; i < 4; ++i) {
      float val[4][4];  // [j][r]
#pragma unroll
      for (int j = 0; j < 4; ++j)
#pragma unroll
        for (int r = 0; r < 4; ++r) val[j][r] = acc[i][j][r] + bz[j];
      if (sec < 2) {
        // RMS over the head's 64 cols: 4 j-regs x 16 fr-lanes (same g, same r)
#pragma unroll
        for (int r = 0; r < 4; ++r) {
          float ss = 0.f;
#pragma unroll
          for (int j = 0; j < 4; ++j) ss += val[j][r] * val[j][r];
#pragma unroll
          for (int mask = 8; mask >= 1; mask >>= 1) ss += __shfl_xor(ss, mask);
          float sc = rsqrtf(ss * (1.0f / 64.0f) + 1e-6f);
#pragma unroll
          for (int j = 0; j < 4; ++j) val[j][r] *= sc * wn_[j];
        }
      }
#pragma unroll
      for (int j = 0; j < 4; ++j) {
        int col = h * 64 + j * 16 + fr;
#pragma unroll
        for (int r = 0; r < 4; ++r) {
          int m = m0 + wm * 64 + i * 16 + r0 + r;
          O[(size_t)m * 1024 + col] = f16_bits(val[j][r]);
        }
      }
    }
  } else {
    float* O = (float*)O0;
#pragma unroll
    for (int j = 0; j < 4; ++j) {
      int n = nw + j * 16 + fr;
#pragma unroll
      for (int i = 0; i < 4; ++i) {
        int mb = m0 + wm * 64 + i * 16 + r0;
#pragma unroll
        for (int r = 0; r < 4; ++r)
          O[(size_t)(mb + r) * 1024 + n] = acc[i][j][r] + bz[j];
      }
    }
  }
}

// ---------------------------------------------------------------------------
// V transpose: v fp16 [8192][1024] -> vt fp16 [bh=128][d=64][n=1024]
// ---------------------------------------------------------------------------
__global__ __launch_bounds__(256) void vtrans16(const u16* __restrict__ v,
                                                u16* __restrict__ vt) {
  __shared__ __align__(16) u16 T[64][80];
  const int t = threadIdx.x;
  const int nb = blockIdx.x;   // 16 n-tiles
  const int bh = blockIdx.y;   // 128
  const int b = bh >> 4, h = bh & 15;
  const int n0 = nb * 64;
#pragma unroll
  for (int u = 0; u < 2; ++u) {
    int idx = u * 256 + t;       // 0..511
    int row = idx >> 3;          // n 0..63
    int c8 = (idx & 7) * 8;      // d chunk
    uint4 val = *(const uint4*)&v[((size_t)(b * 1024 + n0 + row)) * 1024 + h * 64 + c8];
    *(uint4*)&T[row][c8] = val;
  }
  __syncthreads();
#pragma unroll
  for (int u = 0; u < 2; ++u) {
    int idx = u * 256 + t;
    int d = idx >> 3;            // 0..63
    int n8 = (idx & 7) * 8;
    union { u16 q[8]; uint4 v4; } P;
#pragma unroll
    for (int i = 0; i < 8; ++i) P.q[i] = T[n8 + i][d];
    *(uint4*)&vt[((size_t)bh * 64 + d) * 1024 + n0 + n8] = P.v4;
  }
}

// ---------------------------------------------------------------------------
// MFMA flash attention (fp16), 8 waves x 16 q-rows = 128 q-rows/block,
// shared double-buffered K/V LDS (32 KB only), swapped QK^T, and
// REGISTER-ONLY P: the PV A-fragment is assembled from the softmax result
// via intra-wave shuffles (no sP buffer).
//   After swapped QK^T, lane (fr,g) holds p[j][r] = P[q=fr][k=j*16+g*4+r].
//   PV needs      lane (fr,g), half c:  P[q=fr][k=c*32+g*8+m], m=0..7.
//   k = c*32+g*8+m  ->  j_src = 2c+(g>>1); src lanes gg = 2(g&1)(+1).
//   Shfl evaluates the value on the SOURCE lane, so both j-candidates
//   (jA=2c, jB=2c+1) are shuffled and the dest selects by g>>1.
// Grid: 1024 blocks (128 bh x 8 qb) = exactly 4 blocks/CU, zero tail.
// ---------------------------------------------------------------------------
__device__ __forceinline__ void stage_tile64_512(const u16* __restrict__ src,
                                                 u16* __restrict__ lds, int t,
                                                 int rowbase, size_t stride,
                                                 int colbase) {
  int row = t >> 3;                // 0..63
  int cs = (t & 7) ^ (row & 7);    // inverse-swizzled source chunk
  gld_lds16(src + (size_t)(rowbase + row) * stride + colbase + cs * 8,
            lds + (size_t)t * 8);  // wave-uniform base + lane*16B
}

__global__ __launch_bounds__(512) void flash_f16(
    const u16* __restrict__ q, const u16* __restrict__ k,
    const u16* __restrict__ vt, u16* __restrict__ ao_hi,
    u16* __restrict__ ao_lo) {
  __shared__ __align__(16) u16 sK[2][4096];
  __shared__ __align__(16) u16 sV[2][4096];
  const int t = threadIdx.x;
  const int wv = t >> 6, lane = t & 63;
  const int fr = lane & 15;   // q-row within wave
  const int g = lane >> 4;    // k-chunk group
  // Bijective XCD-chunk swizzle: 1024 blocks = 8 xcd x 128.
  int flat = blockIdx.x;
  int nf = (flat & 7) * 128 + (flat >> 3);
  const int qb = nf & 7, bh = nf >> 3;
  const int q0 = qb * 128;
  const int b = bh >> 4, h = bh & 15;

  const u16* qrow = q + ((size_t)(b * 1024 + q0 + wv * 16 + fr)) * 1024 + h * 64;
  const u16* krow = k + ((size_t)b * 1024) * 1024 + h * 64;
  const u16* vbase = vt + (size_t)bh * 64 * 1024;

  // Q fragments: one-time per-lane global read (MFMA B-operand)
  f16x8 aQ[2];
#pragma unroll
  for (int c = 0; c < 2; ++c)
    aQ[c] = *(const f16x8*)&qrow[c * 32 + g * 8];

  float m_run = -1e30f, l_run = 0.f;  // per-lane: stats of q-row `fr`
  float4_t o[4];
  const float4_t zero = {0.f, 0.f, 0.f, 0.f};
#pragma unroll
  for (int dt = 0; dt < 4; ++dt) o[dt] = zero;
  const float scale = 0.125f;

  // Prologue: stage tile 0 into buffer 0 (1 chunk per thread per tile)
  stage_tile64_512(krow, &sK[0][0], t, 0, 1024, 0);
  stage_tile64_512(vbase, &sV[0][0], t, 0, 1024, 0);
  __syncthreads();

  int cur = 0;
  for (int it = 0; it < 16; ++it) {
    const int k0 = it * 64;
    // Issue next-tile stage first (latency hides under compute below)
    if (it < 15) {
      stage_tile64_512(krow, &sK[cur ^ 1][0], t, k0 + 64, 1024, 0);
      stage_tile64_512(vbase, &sV[cur ^ 1][0], t, 0, 1024, k0 + 64);
    }
    const u16* sKc = &sK[cur][0];
    const u16* sVc = &sV[cur][0];

    // Swapped QK^T: lane reg (j,r) = S[q=fr][k0 + j*16 + g*4 + r]
    float4_t sac[4];
#pragma unroll
    for (int j = 0; j < 4; ++j) sac[j] = zero;
#pragma unroll
    for (int j = 0; j < 4; ++j) {
      f16x8 kb0 = *(const f16x8*)&sKc[elem_off(j * 16 + fr, g * 8)];
      f16x8 kb1 = *(const f16x8*)&sKc[elem_off(j * 16 + fr, 32 + g * 8)];
      __builtin_amdgcn_s_setprio(1);
      sac[j] = __builtin_amdgcn_mfma_f32_16x16x32_f16(kb0, aQ[0], sac[j], 0, 0, 0);
      sac[j] = __builtin_amdgcn_mfma_f32_16x16x32_f16(kb1, aQ[1], sac[j], 0, 0, 0);
      __builtin_amdgcn_s_setprio(0);
    }

    // Lane-local softmax (cross-lane only over the 4 g-groups: xor 16, 32)
    float sv[4][4];
    float pmax = -1e30f;
#pragma unroll
    for (int j = 0; j < 4; ++j)
#pragma unroll
      for (int r = 0; r < 4; ++r) {
        sv[j][r] = sac[j][r] * scale;
        pmax = fmaxf(pmax, sv[j][r]);
      }
    pmax = fmaxf(pmax, __shfl_xor(pmax, 16));
    pmax = fmaxf(pmax, __shfl_xor(pmax, 32));
    float m_new = fmaxf(m_run, pmax);
    float corr = __expf(m_run - m_new);
    float rs = 0.f;
    u32 pk[4][2];  // pk[j][h2]: fp16 pair (p[j][2h2], p[j][2h2+1])
#pragma unroll
    for (int j = 0; j < 4; ++j) {
      float p0 = __expf(sv[j][0] - m_new);
      float p1 = __expf(sv[j][1] - m_new);
      float p2 = __expf(sv[j][2] - m_new);
      float p3 = __expf(sv[j][3] - m_new);
      rs += (p0 + p1) + (p2 + p3);
      pk[j][0] = (u32)f16_bits(p0) | ((u32)f16_bits(p1) << 16);
      pk[j][1] = (u32)f16_bits(p2) | ((u32)f16_bits(p3) << 16);
    }
    rs += __shfl_xor(rs, 16);
    rs += __shfl_xor(rs, 32);
    l_run = fmaf(l_run, corr, rs);
    m_run = m_new;

    // Rescale O: o rows are q = g*4+r -> broadcast corr from the owner lane
    // (same g-group; lane g*16 + g*4 + r holds q-row g*4+r's stats).
#pragma unroll
    for (int r = 0; r < 4; ++r) {
      float cr = __shfl(corr, (lane & 48) + ((lane >> 4) << 2) + r);
#pragma unroll
      for (int dt = 0; dt < 4; ++dt) o[dt][r] *= cr;
    }

    // Assemble PV A-fragments in-register via intra-wave shuffles.
    const int s0 = fr + ((g & 1) << 5);  // gg0 = 2*(g&1) -> lane fr+gg0*16
    const int s1 = s0 + 16;              // gg1 = gg0+1
    const bool hi = ((g >> 1) & 1) != 0; // selects j = 2c+1 vs 2c
    f16x8 pa[2];
#pragma unroll
    for (int c = 0; c < 2; ++c) {
      const int jA = 2 * c, jB = 2 * c + 1;
      u32 a0 = (u32)__shfl((int)pk[jA][0], s0);
      u32 a1 = (u32)__shfl((int)pk[jA][1], s0);
      u32 b0 = (u32)__shfl((int)pk[jB][0], s0);
      u32 b1 = (u32)__shfl((int)pk[jB][1], s0);
      u32 a2 = (u32)__shfl((int)pk[jA][0], s1);
      u32 a3 = (u32)__shfl((int)pk[jA][1], s1);
      u32 b2 = (u32)__shfl((int)pk[jB][0], s1);
      u32 b3 = (u32)__shfl((int)pk[jB][1], s1);
      union { u32 w[4]; f16x8 v; } U;
      U.w[0] = hi ? b0 : a0;
      U.w[1] = hi ? b1 : a1;
      U.w[2] = hi ? b2 : a2;
      U.w[3] = hi ? b3 : a3;
      pa[c] = U.v;
    }

    // PV: B-frags from swizzled sV
#pragma unroll
    for (int dt = 0; dt < 4; ++dt) {
      f16x8 vb0 = *(const f16x8*)&sVc[elem_off(dt * 16 + fr, g * 8)];
      f16x8 vb1 = *(const f16x8*)&sVc[elem_off(dt * 16 + fr, 32 + g * 8)];
      __builtin_amdgcn_s_setprio(1);
      o[dt] = __builtin_amdgcn_mfma_f32_16x16x32_f16(pa[0], vb0, o[dt], 0, 0, 0);
      o[dt] = __builtin_amdgcn_mfma_f32_16x16x32_f16(pa[1], vb1, o[dt], 0, 0, 0);
      __builtin_amdgcn_s_setprio(0);
    }

    // Drain stage -> next tile ready; swap buffers
    __syncthreads();
    cur ^= 1;
  }

  // Epilogue: normalize (l for row g*4+r from its owner lane), split bf16
  // hi/lo for the split proj GEMM.
#pragma unroll
  for (int r = 0; r < 4; ++r) {
    float lq = __shfl(l_run, (lane & 48) + ((lane >> 4) << 2) + r);
    float inv = 1.0f / lq;
    int qg = q0 + wv * 16 + g * 4 + r;
#pragma unroll
    for (int dt = 0; dt < 4; ++dt) {
      float v = o[dt][r] * inv;
      u16 hb = f32_to_bf16(v);
      size_t off = ((size_t)(b * 1024 + qg)) * 1024 + h * 64 + dt * 16 + fr;
      ao_hi[off] = hb;
      ao_lo[off] = f32_to_bf16(v - bf16_to_f32(hb));
    }
  }
}

// ---------------------------------------------------------------------------
extern "C" void kernel_launch(void* const* d_in, const int* in_sizes, int n_in,
                              void* d_out, int out_size, void* d_ws, size_t ws_size,
                              hipStream_t stream) {
  const float* x      = (const float*)d_in[0];
  const float* w_qkv  = (const float*)d_in[1];
  const float* b_qkv  = (const float*)d_in[2];
  const float* qn_w   = (const float*)d_in[3];
  const float* kn_w   = (const float*)d_in[4];
  const float* w_proj = (const float*)d_in[5];
  const float* b_proj = (const float*)d_in[6];
  float* out = (float*)d_out;

  // ws layout, all u16 (~144 MB)
  u16* x_hi  = (u16*)d_ws;          // 8192*1024
  u16* x_lo  = x_hi + 8388608;
  u16* wq_hi = x_lo + 8388608;      // 3072*1024
  u16* wq_lo = wq_hi + 3145728;
  u16* wp_hi = wq_lo + 3145728;     // 1024*1024
  u16* wp_lo = wp_hi + 1048576;
  u16* qb    = wp_lo + 1048576;     // fp16 q [8192][1024]
  u16* kb    = qb + 8388608;        // fp16 k
  u16* vb    = kb + 8388608;        // fp16 v
  u16* vtb   = vb + 8388608;        // fp16 v^T [128][64][1024]
  u16* ao_hi = vtb + 8388608;       // bf16 attn-out hi
  u16* ao_lo = ao_hi + 8388608;     // bf16 attn-out lo

  split_bf16<<<8192, 256, 0, stream>>>(x, x_hi, x_lo);
  split_bf16<<<3072, 256, 0, stream>>>(w_qkv, wq_hi, wq_lo);
  split_bf16<<<1024, 256, 0, stream>>>(w_proj, wp_hi, wp_lo);

  // QKV projection (split-bf16, fp32-grade) + fused RMSNorm -> fp16 q,k,v
  gemm_split<0><<<dim3(QKV_N / 128, M_ROWS / 128), 256, 0, stream>>>(
      x_hi, x_lo, wq_hi, wq_lo, b_qkv, qb, kb, vb, qn_w, kn_w,
      M_ROWS, QKV_N, C_DIM);

  vtrans16<<<dim3(16, 128), 256, 0, stream>>>(vb, vtb);

  flash_f16<<<1024, 512, 0, stream>>>(qb, kb, vtb, ao_hi, ao_lo);

  // Output projection (split-bf16) -> fp32 out
  gemm_split<1><<<dim3(C_DIM / 128, M_ROWS / 128), 256, 0, stream>>>(
      ao_hi, ao_lo, wp_hi, wp_lo, b_proj, out, nullptr, nullptr,
      nullptr, nullptr, M_ROWS, C_DIM, C_DIM);
}

// Round 14
// 390.694 us; speedup vs baseline: 1.4547x; 1.0279x over previous
//
#include <hip/hip_runtime.h>
#include <hip/hip_bf16.h>
#include <stdint.h>

// Problem constants: B=8, N=1024, C=1024, H=16, D=64, M=B*N=8192
#define M_ROWS 8192
#define C_DIM  1024
#define QKV_N  3072

typedef _Float16 f16;
typedef __attribute__((ext_vector_type(8))) _Float16 f16x8;   // 4 VGPRs
typedef __attribute__((ext_vector_type(8))) short short8_t;   // 8 bf16
typedef __attribute__((ext_vector_type(4))) float float4_t;   // 4 fp32 acc
typedef unsigned short u16;
typedef unsigned int u32;

__device__ __forceinline__ u16 f16_bits(float x) {
  union { f16 h; u16 u; } c; c.h = (f16)x; return c.u;
}
__device__ __forceinline__ u16 f32_to_bf16(float f) {
  u32 u = __float_as_uint(f);
  u32 r = (u + 0x7fffu + ((u >> 16) & 1u)) >> 16;  // RNE
  return (u16)r;
}
__device__ __forceinline__ float bf16_to_f32(u16 h) {
  return __uint_as_float((u32)h << 16);
}
__device__ __forceinline__ void gld_lds16(const void* g, void* l) {
  __builtin_amdgcn_global_load_lds(
      (const __attribute__((address_space(1))) u32*)g,
      (__attribute__((address_space(3))) u32*)l, 16, 0, 0);
}
// Swizzled elem offset in a [64][64]-fp16 LDS tile (row len 128B):
// byte ^= ((row&7)<<4)  <=>  elem ^= ((row&7)<<3)
__device__ __forceinline__ int elem_off(int row, int e0) {
  return row * 64 + (e0 ^ ((row & 7) << 3));
}

// ---------------------------------------------------------------------------
// split fp32 -> (hi, lo) bf16 pair; 4 elems/thread
// ---------------------------------------------------------------------------
__global__ __launch_bounds__(256) void split_bf16(
    const float* __restrict__ in, u16* __restrict__ hi, u16* __restrict__ lo) {
  int i = blockIdx.x * 256 + threadIdx.x;
  float4 v = ((const float4*)in)[i];
  float x[4] = {v.x, v.y, v.z, v.w};
  union { u16 u[4]; uint2 v2; } H, L;
#pragma unroll
  for (int j = 0; j < 4; ++j) {
    u16 h = f32_to_bf16(x[j]);
    H.u[j] = h;
    L.u[j] = f32_to_bf16(x[j] - bf16_to_f32(h));
  }
  ((uint2*)hi)[i] = H.v2;
  ((uint2*)lo)[i] = L.v2;
}

// ---------------------------------------------------------------------------
// Split-bf16 MFMA GEMM (Ah+Al)@(Bh+Bl)^T + bias, drops Al*Bl (fp32-grade).
// 128x128 tile, BK=32, 256 thr (4 waves 2x2), 16x16x32_bf16.
// T3/T4 schedule: DOUBLE-BUFFERED LDS + COUNTED vmcnt + raw barriers —
// prefetch for tile t+1 stays in flight across tile t's compute; each wave
// waits its own vmcnt(8) (= this iter's 8 new gld_lds outstanding) BEFORE
// the barrier, so post-barrier all waves' tile-t data is resident.
// MODE 0: QKV — fused per-head RMSNorm on sections 0,1; writes fp16 q,k,v.
// MODE 1: proj — fp32 + bias to O0 (the final output).
// ---------------------------------------------------------------------------
template <int MODE>
__global__ __launch_bounds__(256) void gemm_split(
    const u16* __restrict__ Ah, const u16* __restrict__ Al,
    const u16* __restrict__ Bh, const u16* __restrict__ Bl,
    const float* __restrict__ bias, void* __restrict__ O0,
    void* __restrict__ O1, void* __restrict__ O2,
    const float* __restrict__ qn_w, const float* __restrict__ kn_w,
    int M, int N, int K) {
  __shared__ u16 sAh[2 * 4096], sAl[2 * 4096], sBh[2 * 4096], sBl[2 * 4096];
  const int t = threadIdx.x;
  const int wv = t >> 6;
  const int lane = t & 63;
  const int n0 = blockIdx.x * 128;
  const int m0 = blockIdx.y * 128;
  const int wm = wv >> 1, wn = wv & 1;
  const int fr = lane & 15;
  const int g = lane >> 4;
  const int kfr = g * 8;

  float4_t acc[4][4];
  const float4_t zero = {0.f, 0.f, 0.f, 0.f};
#pragma unroll
  for (int i = 0; i < 4; ++i)
#pragma unroll
    for (int j = 0; j < 4; ++j) acc[i][j] = zero;

  // Stage one BK=32 tile-set into buffer `buf` (8 gld_lds per thread).
  auto stage = [&](int buf, int k0) {
#pragma unroll
    for (int u = 0; u < 2; ++u) {
      int idx = u * 256 + t;
      int row = idx >> 2;
      int ke = (idx & 3) * 8;
      int ldsoff = buf * 4096 + (u * 256 + wv * 64) * 8;  // wave-uniform base
      const size_t ga = (size_t)(m0 + row) * K + k0 + ke;
      const size_t gb = (size_t)(n0 + row) * K + k0 + ke;
      gld_lds16(Ah + ga, sAh + ldsoff);
      gld_lds16(Al + ga, sAl + ldsoff);
      gld_lds16(Bh + gb, sBh + ldsoff);
      gld_lds16(Bl + gb, sBl + ldsoff);
    }
  };

  // Prologue: tile 0 into buffer 0 (8 loads in flight).
  stage(0, 0);
  int cur = 0;
  const int KT = K >> 5;
  for (int kt = 0; kt < KT; ++kt) {
    if (kt + 1 < KT) {
      stage(cur ^ 1, (kt + 1) << 5);  // +8 loads (tile t+1), 16 outstanding
      asm volatile("s_waitcnt vmcnt(8)" ::: "memory");  // oldest 8 = tile t done
    } else {
      asm volatile("s_waitcnt vmcnt(0)" ::: "memory");  // last tile: drain
    }
    __builtin_amdgcn_s_barrier();     // all waves have their tile-t data
    asm volatile("" ::: "memory");

    const u16* pAh = sAh + cur * 4096;
    const u16* pAl = sAl + cur * 4096;
    const u16* pBh = sBh + cur * 4096;
    const u16* pBl = sBl + cur * 4096;
    short8_t ah[4], al[4], bh[4], bl[4];
#pragma unroll
    for (int i = 0; i < 4; ++i) {
      ah[i] = *(const short8_t*)&pAh[(wm * 64 + i * 16 + fr) * 32 + kfr];
      al[i] = *(const short8_t*)&pAl[(wm * 64 + i * 16 + fr) * 32 + kfr];
      bh[i] = *(const short8_t*)&pBh[(wn * 64 + i * 16 + fr) * 32 + kfr];
      bl[i] = *(const short8_t*)&pBl[(wn * 64 + i * 16 + fr) * 32 + kfr];
    }
#pragma unroll
    for (int i = 0; i < 4; ++i)
#pragma unroll
      for (int j = 0; j < 4; ++j) {
        acc[i][j] = __builtin_amdgcn_mfma_f32_16x16x32_bf16(ah[i], bh[j], acc[i][j], 0, 0, 0);
        acc[i][j] = __builtin_amdgcn_mfma_f32_16x16x32_bf16(ah[i], bl[j], acc[i][j], 0, 0, 0);
        acc[i][j] = __builtin_amdgcn_mfma_f32_16x16x32_bf16(al[i], bh[j], acc[i][j], 0, 0, 0);
      }
    // All ds_reads are consumed by the MFMAs above (compiler lgkmcnt), so a
    // raw barrier suffices before the next iteration overwrites buf[cur].
    asm volatile("" ::: "memory");
    __builtin_amdgcn_s_barrier();
    cur ^= 1;
  }

  // Epilogue. C/D layout: col=lane&15, row=(lane>>4)*4+reg.
  const int r0 = g * 4;
  const int nw = n0 + wn * 64;  // wave col base; 64-aligned -> exactly 1 head
  float bz[4];
#pragma unroll
  for (int j = 0; j < 4; ++j) bz[j] = bias[nw + j * 16 + fr];

  if (MODE == 0) {
    const int sec = nw >> 10;           // 0=q 1=k 2=v
    const int h = (nw >> 6) & 15;
    u16* O = (sec == 0) ? (u16*)O0 : ((sec == 1) ? (u16*)O1 : (u16*)O2);
    float wn_[4];
    if (sec < 2) {
      const float* wvec = (sec == 0) ? qn_w : kn_w;
#pragma unroll
      for (int j = 0; j < 4; ++j) wn_[j] = wvec[j * 16 + fr];
    }
#pragma unroll
    for (int i = 0; i < 4; ++i) {
      float val[4][4];  // [j][r]
#pragma unroll
      for (int j = 0; j < 4; ++j)
#pragma unroll
        for (int r = 0; r < 4; ++r) val[j][r] = acc[i][j][r] + bz[j];
      if (sec < 2) {
        // RMS over the head's 64 cols: 4 j-regs x 16 fr-lanes (same g, same r)
#pragma unroll
        for (int r = 0; r < 4; ++r) {
          float ss = 0.f;
#pragma unroll
          for (int j = 0; j < 4; ++j) ss += val[j][r] * val[j][r];
#pragma unroll
          for (int mask = 8; mask >= 1; mask >>= 1) ss += __shfl_xor(ss, mask);
          float sc = rsqrtf(ss * (1.0f / 64.0f) + 1e-6f);
#pragma unroll
          for (int j = 0; j < 4; ++j) val[j][r] *= sc * wn_[j];
        }
      }
#pragma unroll
      for (int j = 0; j < 4; ++j) {
        int col = h * 64 + j * 16 + fr;
#pragma unroll
        for (int r = 0; r < 4; ++r) {
          int m = m0 + wm * 64 + i * 16 + r0 + r;
          O[(size_t)m * 1024 + col] = f16_bits(val[j][r]);
        }
      }
    }
  } else {
    float* O = (float*)O0;
#pragma unroll
    for (int j = 0; j < 4; ++j) {
      int n = nw + j * 16 + fr;
#pragma unroll
      for (int i = 0; i < 4; ++i) {
        int mb = m0 + wm * 64 + i * 16 + r0;
#pragma unroll
        for (int r = 0; r < 4; ++r)
          O[(size_t)(mb + r) * 1024 + n] = acc[i][j][r] + bz[j];
      }
    }
  }
}

// ---------------------------------------------------------------------------
// V transpose: v fp16 [8192][1024] -> vt fp16 [bh=128][d=64][n=1024]
// ---------------------------------------------------------------------------
__global__ __launch_bounds__(256) void vtrans16(const u16* __restrict__ v,
                                                u16* __restrict__ vt) {
  __shared__ __align__(16) u16 T[64][80];
  const int t = threadIdx.x;
  const int nb = blockIdx.x;   // 16 n-tiles
  const int bh = blockIdx.y;   // 128
  const int b = bh >> 4, h = bh & 15;
  const int n0 = nb * 64;
#pragma unroll
  for (int u = 0; u < 2; ++u) {
    int idx = u * 256 + t;       // 0..511
    int row = idx >> 3;          // n 0..63
    int c8 = (idx & 7) * 8;      // d chunk
    uint4 val = *(const uint4*)&v[((size_t)(b * 1024 + n0 + row)) * 1024 + h * 64 + c8];
    *(uint4*)&T[row][c8] = val;
  }
  __syncthreads();
#pragma unroll
  for (int u = 0; u < 2; ++u) {
    int idx = u * 256 + t;
    int d = idx >> 3;            // 0..63
    int n8 = (idx & 7) * 8;
    union { u16 q[8]; uint4 v4; } P;
#pragma unroll
    for (int i = 0; i < 8; ++i) P.q[i] = T[n8 + i][d];
    *(uint4*)&vt[((size_t)bh * 64 + d) * 1024 + n0 + n8] = P.v4;
  }
}

// ---------------------------------------------------------------------------
// MFMA flash attention (fp16), 8 waves x 16 q-rows = 128 q-rows/block,
// shared double-buffered K/V LDS (32 KB), swapped QK^T, register-only P
// (PV A-fragment assembled via intra-wave shuffles). Unchanged from R12.
// ---------------------------------------------------------------------------
__device__ __forceinline__ void stage_tile64_512(const u16* __restrict__ src,
                                                 u16* __restrict__ lds, int t,
                                                 int rowbase, size_t stride,
                                                 int colbase) {
  int row = t >> 3;                // 0..63
  int cs = (t & 7) ^ (row & 7);    // inverse-swizzled source chunk
  gld_lds16(src + (size_t)(rowbase + row) * stride + colbase + cs * 8,
            lds + (size_t)t * 8);  // wave-uniform base + lane*16B
}

__global__ __launch_bounds__(512) void flash_f16(
    const u16* __restrict__ q, const u16* __restrict__ k,
    const u16* __restrict__ vt, u16* __restrict__ ao_hi,
    u16* __restrict__ ao_lo) {
  __shared__ __align__(16) u16 sK[2][4096];
  __shared__ __align__(16) u16 sV[2][4096];
  const int t = threadIdx.x;
  const int wv = t >> 6, lane = t & 63;
  const int fr = lane & 15;   // q-row within wave
  const int g = lane >> 4;    // k-chunk group
  // Bijective XCD-chunk swizzle: 1024 blocks = 8 xcd x 128.
  int flat = blockIdx.x;
  int nf = (flat & 7) * 128 + (flat >> 3);
  const int qb = nf & 7, bh = nf >> 3;
  const int q0 = qb * 128;
  const int b = bh >> 4, h = bh & 15;

  const u16* qrow = q + ((size_t)(b * 1024 + q0 + wv * 16 + fr)) * 1024 + h * 64;
  const u16* krow = k + ((size_t)b * 1024) * 1024 + h * 64;
  const u16* vbase = vt + (size_t)bh * 64 * 1024;

  f16x8 aQ[2];
#pragma unroll
  for (int c = 0; c < 2; ++c)
    aQ[c] = *(const f16x8*)&qrow[c * 32 + g * 8];

  float m_run = -1e30f, l_run = 0.f;  // per-lane: stats of q-row `fr`
  float4_t o[4];
  const float4_t zero = {0.f, 0.f, 0.f, 0.f};
#pragma unroll
  for (int dt = 0; dt < 4; ++dt) o[dt] = zero;
  const float scale = 0.125f;

  stage_tile64_512(krow, &sK[0][0], t, 0, 1024, 0);
  stage_tile64_512(vbase, &sV[0][0], t, 0, 1024, 0);
  __syncthreads();

  int cur = 0;
  for (int it = 0; it < 16; ++it) {
    const int k0 = it * 64;
    if (it < 15) {
      stage_tile64_512(krow, &sK[cur ^ 1][0], t, k0 + 64, 1024, 0);
      stage_tile64_512(vbase, &sV[cur ^ 1][0], t, 0, 1024, k0 + 64);
    }
    const u16* sKc = &sK[cur][0];
    const u16* sVc = &sV[cur][0];

    // Swapped QK^T: lane reg (j,r) = S[q=fr][k0 + j*16 + g*4 + r]
    float4_t sac[4];
#pragma unroll
    for (int j = 0; j < 4; ++j) sac[j] = zero;
#pragma unroll
    for (int j = 0; j < 4; ++j) {
      f16x8 kb0 = *(const f16x8*)&sKc[elem_off(j * 16 + fr, g * 8)];
      f16x8 kb1 = *(const f16x8*)&sKc[elem_off(j * 16 + fr, 32 + g * 8)];
      __builtin_amdgcn_s_setprio(1);
      sac[j] = __builtin_amdgcn_mfma_f32_16x16x32_f16(kb0, aQ[0], sac[j], 0, 0, 0);
      sac[j] = __builtin_amdgcn_mfma_f32_16x16x32_f16(kb1, aQ[1], sac[j], 0, 0, 0);
      __builtin_amdgcn_s_setprio(0);
    }

    // Lane-local softmax (cross-lane only over the 4 g-groups: xor 16, 32)
    float sv[4][4];
    float pmax = -1e30f;
#pragma unroll
    for (int j = 0; j < 4; ++j)
#pragma unroll
      for (int r = 0; r < 4; ++r) {
        sv[j][r] = sac[j][r] * scale;
        pmax = fmaxf(pmax, sv[j][r]);
      }
    pmax = fmaxf(pmax, __shfl_xor(pmax, 16));
    pmax = fmaxf(pmax, __shfl_xor(pmax, 32));
    float m_new = fmaxf(m_run, pmax);
    float corr = __expf(m_run - m_new);
    float rs = 0.f;
    u32 pk[4][2];  // pk[j][h2]: fp16 pair (p[j][2h2], p[j][2h2+1])
#pragma unroll
    for (int j = 0; j < 4; ++j) {
      float p0 = __expf(sv[j][0] - m_new);
      float p1 = __expf(sv[j][1] - m_new);
      float p2 = __expf(sv[j][2] - m_new);
      float p3 = __expf(sv[j][3] - m_new);
      rs += (p0 + p1) + (p2 + p3);
      pk[j][0] = (u32)f16_bits(p0) | ((u32)f16_bits(p1) << 16);
      pk[j][1] = (u32)f16_bits(p2) | ((u32)f16_bits(p3) << 16);
    }
    rs += __shfl_xor(rs, 16);
    rs += __shfl_xor(rs, 32);
    l_run = fmaf(l_run, corr, rs);
    m_run = m_new;

    // Rescale O: o rows are q = g*4+r -> broadcast corr from the owner lane
#pragma unroll
    for (int r = 0; r < 4; ++r) {
      float cr = __shfl(corr, (lane & 48) + ((lane >> 4) << 2) + r);
#pragma unroll
      for (int dt = 0; dt < 4; ++dt) o[dt][r] *= cr;
    }

    // Assemble PV A-fragments in-register via intra-wave shuffles.
    const int s0 = fr + ((g & 1) << 5);  // gg0 = 2*(g&1) -> lane fr+gg0*16
    const int s1 = s0 + 16;              // gg1 = gg0+1
    const bool hi = ((g >> 1) & 1) != 0; // selects j = 2c+1 vs 2c
    f16x8 pa[2];
#pragma unroll
    for (int c = 0; c < 2; ++c) {
      const int jA = 2 * c, jB = 2 * c + 1;
      u32 a0 = (u32)__shfl((int)pk[jA][0], s0);
      u32 a1 = (u32)__shfl((int)pk[jA][1], s0);
      u32 b0 = (u32)__shfl((int)pk[jB][0], s0);
      u32 b1 = (u32)__shfl((int)pk[jB][1], s0);
      u32 a2 = (u32)__shfl((int)pk[jA][0], s1);
      u32 a3 = (u32)__shfl((int)pk[jA][1], s1);
      u32 b2 = (u32)__shfl((int)pk[jB][0], s1);
      u32 b3 = (u32)__shfl((int)pk[jB][1], s1);
      union { u32 w[4]; f16x8 v; } U;
      U.w[0] = hi ? b0 : a0;
      U.w[1] = hi ? b1 : a1;
      U.w[2] = hi ? b2 : a2;
      U.w[3] = hi ? b3 : a3;
      pa[c] = U.v;
    }

    // PV: B-frags from swizzled sV
#pragma unroll
    for (int dt = 0; dt < 4; ++dt) {
      f16x8 vb0 = *(const f16x8*)&sVc[elem_off(dt * 16 + fr, g * 8)];
      f16x8 vb1 = *(const f16x8*)&sVc[elem_off(dt * 16 + fr, 32 + g * 8)];
      __builtin_amdgcn_s_setprio(1);
      o[dt] = __builtin_amdgcn_mfma_f32_16x16x32_f16(pa[0], vb0, o[dt], 0, 0, 0);
      o[dt] = __builtin_amdgcn_mfma_f32_16x16x32_f16(pa[1], vb1, o[dt], 0, 0, 0);
      __builtin_amdgcn_s_setprio(0);
    }

    __syncthreads();
    cur ^= 1;
  }

  // Epilogue: normalize, split bf16 hi/lo for the split proj GEMM.
#pragma unroll
  for (int r = 0; r < 4; ++r) {
    float lq = __shfl(l_run, (lane & 48) + ((lane >> 4) << 2) + r);
    float inv = 1.0f / lq;
    int qg = q0 + wv * 16 + g * 4 + r;
#pragma unroll
    for (int dt = 0; dt < 4; ++dt) {
      float v = o[dt][r] * inv;
      u16 hb = f32_to_bf16(v);
      size_t off = ((size_t)(b * 1024 + qg)) * 1024 + h * 64 + dt * 16 + fr;
      ao_hi[off] = hb;
      ao_lo[off] = f32_to_bf16(v - bf16_to_f32(hb));
    }
  }
}

// ---------------------------------------------------------------------------
extern "C" void kernel_launch(void* const* d_in, const int* in_sizes, int n_in,
                              void* d_out, int out_size, void* d_ws, size_t ws_size,
                              hipStream_t stream) {
  const float* x      = (const float*)d_in[0];
  const float* w_qkv  = (const float*)d_in[1];
  const float* b_qkv  = (const float*)d_in[2];
  const float* qn_w   = (const float*)d_in[3];
  const float* kn_w   = (const float*)d_in[4];
  const float* w_proj = (const float*)d_in[5];
  const float* b_proj = (const float*)d_in[6];
  float* out = (float*)d_out;

  // ws layout, all u16 (~144 MB)
  u16* x_hi  = (u16*)d_ws;          // 8192*1024
  u16* x_lo  = x_hi + 8388608;
  u16* wq_hi = x_lo + 8388608;      // 3072*1024
  u16* wq_lo = wq_hi + 3145728;
  u16* wp_hi = wq_lo + 3145728;     // 1024*1024
  u16* wp_lo = wp_hi + 1048576;
  u16* qb    = wp_lo + 1048576;     // fp16 q [8192][1024]
  u16* kb    = qb + 8388608;        // fp16 k
  u16* vb    = kb + 8388608;        // fp16 v
  u16* vtb   = vb + 8388608;        // fp16 v^T [128][64][1024]
  u16* ao_hi = vtb + 8388608;       // bf16 attn-out hi
  u16* ao_lo = ao_hi + 8388608;     // bf16 attn-out lo

  split_bf16<<<8192, 256, 0, stream>>>(x, x_hi, x_lo);
  split_bf16<<<3072, 256, 0, stream>>>(w_qkv, wq_hi, wq_lo);
  split_bf16<<<1024, 256, 0, stream>>>(w_proj, wp_hi, wp_lo);

  // QKV projection (split-bf16, fp32-grade) + fused RMSNorm -> fp16 q,k,v
  gemm_split<0><<<dim3(QKV_N / 128, M_ROWS / 128), 256, 0, stream>>>(
      x_hi, x_lo, wq_hi, wq_lo, b_qkv, qb, kb, vb, qn_w, kn_w,
      M_ROWS, QKV_N, C_DIM);

  vtrans16<<<dim3(16, 128), 256, 0, stream>>>(vb, vtb);

  flash_f16<<<1024, 512, 0, stream>>>(qb, kb, vtb, ao_hi, ao_lo);

  // Output projection (split-bf16) -> fp32 out
  gemm_split<1><<<dim3(C_DIM / 128, M_ROWS / 128), 256, 0, stream>>>(
      ao_hi, ao_lo, wp_hi, wp_lo, b_proj, out, nullptr, nullptr,
      nullptr, nullptr, M_ROWS, C_DIM, C_DIM);
}